// Round 5
// baseline (247.669 us; speedup 1.0000x reference)
//
#include <hip/hip_runtime.h>
#include <hip/hip_fp16.h>

// GAT regression: 2-layer GAT + linear head.
// R12: agg kernels restructured around ONE EDGE PER WAVE-INSTRUCTION:
//  - 64 lanes x 1 dword = exactly one 256B H row (agg1) / 2 edges x 128B (agg2)
//    -> minimum TA cost (every quarter-wave = one 64B line), no over-read.
//  - row index p becomes wave-uniform via readlane -> SGPR base + saddr loads
//    (~1 VALU/edge addressing instead of ~6).
//  - p/w batched 8 edges per vector load, distributed via readlane / width-8
//    shfl (DS pipe, off the TA).
//  - lane owns 2 channels: acc = 2 regs; agg1 den needs NO reduction and the
//    epilogue has zero shuffles; agg2 needs one xor-32 combine.
// R11 retained: ew1/ew2 precompute per-edge exp weights; f16 H rows (fma_mix).
// Requires N < 65536 (16-bit packing). N = 50000.

#define LEAKY(x) ((x) > 0.f ? (x) : 0.2f * (x))

__device__ inline unsigned h16pack(float a, float b) {
  union { __half h[2]; unsigned u; } cv;
  cv.h[0] = __float2half(a);
  cv.h[1] = __float2half(b);
  return cv.u;
}

// ---------------- bucketed CSR build ----------------

template <int VPT>
__global__ __launch_bounds__(256) void bucket_cnt_kernel(const int* __restrict__ ei, int E, int n,
                                                         int* __restrict__ bc) {
  __shared__ int lc[256];
  int t = threadIdx.x;
  lc[t] = 0;
  __syncthreads();
  int base = blockIdx.x * (256 * VPT) + t;
  int tot = E + n;
#pragma unroll
  for (int u = 0; u < VPT; ++u) {
    int i = base + u * 256;
    if (i < tot) {
      int d = (i < E) ? ei[E + i] : (i - E);
      atomicAdd(&lc[d >> 8], 1);
    }
  }
  __syncthreads();
  if (lc[t]) atomicAdd(&bc[t], lc[t]);
}

__global__ __launch_bounds__(256) void bucket_scan_kernel(const int* __restrict__ bc,
                                                          int* __restrict__ boff,
                                                          int* __restrict__ bcur, int B,
                                                          int* __restrict__ off, int n, int Etot) {
  __shared__ int sm[256];
  int t = threadIdx.x;
  int v = (t < B) ? bc[t] : 0;
  sm[t] = v;
  __syncthreads();
  for (int s = 1; s < 256; s <<= 1) {
    int a = (t >= s) ? sm[t - s] : 0;
    __syncthreads();
    sm[t] += a;
    __syncthreads();
  }
  int excl = sm[t] - v;
  if (t < B) { boff[t] = excl; bcur[t] = excl; }
  if (t == 0) { boff[B] = Etot; off[n] = Etot; }
}

template <int VPT>
__global__ __launch_bounds__(256) void bucket_scatter_kernel(const int* __restrict__ ei, int E,
                                                             int n, int* __restrict__ bcur,
                                                             unsigned* __restrict__ entries) {
  __shared__ int lc[256];
  __shared__ int lbase[256];
  int t = threadIdx.x;
  lc[t] = 0;
  __syncthreads();
  int base = blockIdx.x * (256 * VPT) + t;
  int tot = E + n;
  int bb[VPT], ll[VPT];
  unsigned pk[VPT];
#pragma unroll
  for (int u = 0; u < VPT; ++u) {
    int i = base + u * 256;
    bb[u] = -1;
    if (i < tot) {
      int s, d;
      if (i < E) { s = ei[i]; d = ei[E + i]; }
      else       { s = d = i - E; }
      int b = d >> 8;
      bb[u] = b;
      ll[u] = atomicAdd(&lc[b], 1);
      pk[u] = (unsigned)s | ((unsigned)(d & 255) << 16);
    }
  }
  __syncthreads();
  if (lc[t]) lbase[t] = atomicAdd(&bcur[t], lc[t]);
  __syncthreads();
#pragma unroll
  for (int u = 0; u < VPT; ++u)
    if (bb[u] >= 0) entries[lbase[bb[u]] + ll[u]] = pk[u];
}

__global__ __launch_bounds__(256) void csr_build_kernel(const unsigned* __restrict__ entries,
                                                        const int* __restrict__ boff,
                                                        int* __restrict__ off,
                                                        unsigned* __restrict__ epair, int n) {
  __shared__ int hist[256];
  __shared__ int scn[256];
  __shared__ int cur[256];
  int b = blockIdx.x, t = threadIdx.x;
  int k0 = boff[b], k1 = boff[b + 1];
  hist[t] = 0;
  __syncthreads();
  for (int k = k0 + t; k < k1; k += 256) atomicAdd(&hist[(entries[k] >> 16) & 255], 1);
  __syncthreads();
  int v = hist[t];
  scn[t] = v;
  __syncthreads();
  for (int s = 1; s < 256; s <<= 1) {
    int a = (t >= s) ? scn[t - s] : 0;
    __syncthreads();
    scn[t] += a;
    __syncthreads();
  }
  int excl = scn[t] - v;
  int d = (b << 8) + t;
  if (d < n) off[d] = k0 + excl;
  cur[t] = k0 + excl;
  __syncthreads();
  unsigned dbase = (unsigned)(b << 8) << 16;
  for (int k = k0 + t; k < k1; k += 256) {
    unsigned e = entries[k];
    unsigned dl = (e >> 16) & 255;
    int p = atomicAdd(&cur[dl], 1);
    epair[p] = (e & 0xffffu) | (dbase + (dl << 16));
  }
}

// ---------------- fused GEMM + logits (W via L1/L2, X tile in LDS) -----------

template <int K, int M, int NODES, int HEADS>
__global__ __launch_bounds__(256) void gemm_logits_kernel(const float* __restrict__ X,
                                                          const float* __restrict__ W,
                                                          const float* __restrict__ a_src,
                                                          const float* __restrict__ a_dst,
                                                          unsigned short* __restrict__ Hb,
                                                          float2* __restrict__ als,
                                                          float2* __restrict__ ald, int n) {
  constexpr int JPER = 4;
  constexpr int NSLOT = M / JPER;
  constexpr int SLOTS = 256 / NSLOT;
  constexpr int PER = NODES / SLOTS;
  __shared__ float Xl[NODES * K];

  int t = threadIdx.x;
  int nb0 = blockIdx.x * NODES;

  for (int i = t; i < NODES * K / 4; i += 256) {
    int r = i / (K / 4);
    int c = i % (K / 4);
    int node = nb0 + r;
    int nc = node < n ? node : (n - 1);
    ((float4*)Xl)[i] = ((const float4*)(X + (size_t)nc * K))[c];
  }
  __syncthreads();

  int j0 = (t % NSLOT) * JPER;
  int slot = t / NSLOT;
  const float4* Wg = (const float4*)W;

  float4 Asv = *(const float4*)(a_src + j0);
  float4 Adv = *(const float4*)(a_dst + j0);

  float acc[PER][JPER];
#pragma unroll
  for (int s = 0; s < PER; ++s)
#pragma unroll
    for (int q = 0; q < JPER; ++q) acc[s][q] = 0.f;

  for (int k4 = 0; k4 < K / 4; ++k4) {
    float4 w0 = Wg[(k4 * 4 + 0) * (M / 4) + (j0 >> 2)];
    float4 w1 = Wg[(k4 * 4 + 1) * (M / 4) + (j0 >> 2)];
    float4 w2 = Wg[(k4 * 4 + 2) * (M / 4) + (j0 >> 2)];
    float4 w3 = Wg[(k4 * 4 + 3) * (M / 4) + (j0 >> 2)];
#pragma unroll
    for (int s = 0; s < PER; ++s) {
      float4 xv = ((const float4*)Xl)[(slot * PER + s) * (K / 4) + k4];
      acc[s][0] += xv.x * w0.x + xv.y * w1.x + xv.z * w2.x + xv.w * w3.x;
      acc[s][1] += xv.x * w0.y + xv.y * w1.y + xv.z * w2.y + xv.w * w3.y;
      acc[s][2] += xv.x * w0.z + xv.y * w1.z + xv.z * w2.z + xv.w * w3.z;
      acc[s][3] += xv.x * w0.w + xv.y * w1.w + xv.z * w2.w + xv.w * w3.w;
    }
  }

#pragma unroll
  for (int s = 0; s < PER; ++s) {
    int node = nb0 + slot * PER + s;
    if (node < n) {
      uint2 b;
      b.x = h16pack(acc[s][0], acc[s][1]);
      b.y = h16pack(acc[s][2], acc[s][3]);
      *(uint2*)(Hb + (size_t)node * M + j0) = b;
    }
    float ps = acc[s][0] * Asv.x + acc[s][1] * Asv.y + acc[s][2] * Asv.z + acc[s][3] * Asv.w;
    float pd = acc[s][0] * Adv.x + acc[s][1] * Adv.y + acc[s][2] * Adv.z + acc[s][3] * Adv.w;
#pragma unroll
    for (int m = 1; m <= 8; m <<= 1) {
      ps += __shfl_xor(ps, m, 64);
      pd += __shfl_xor(pd, m, 64);
    }
    if (HEADS == 2) {
      float ps_o = __shfl_xor(ps, 16, 64);
      float pd_o = __shfl_xor(pd, 16, 64);
      if ((t & 31) == 0 && node < n) {
        als[node] = make_float2(ps, ps_o);
        ald[node] = make_float2(pd, pd_o);
      }
    } else {
      if ((t & 15) == 0 && node < n) als[node] = make_float2(ps, pd);
    }
  }
}

// ---------------- per-edge exp-weight kernels (streaming) ----------------

__global__ __launch_bounds__(256) void ew1_kernel(const unsigned* __restrict__ epair,
                                                  const float2* __restrict__ als,
                                                  const float2* __restrict__ ald,
                                                  float* __restrict__ gwa,
                                                  float* __restrict__ gwb, int Etot) {
  int i = blockIdx.x * 256 + threadIdx.x;
  if (i >= Etot) return;
  unsigned pp = epair[i];
  float2 l = als[pp & 0xffffu];
  float2 d = ald[pp >> 16];
  float x0 = LEAKY(l.x + d.x);
  float x1 = LEAKY(l.y + d.y);
  gwa[i] = __expf(x0);
  gwb[i] = __expf(x1);
}

__global__ __launch_bounds__(256) void ew2_kernel(const unsigned* __restrict__ epair,
                                                  const float2* __restrict__ al2,
                                                  float* __restrict__ gw, int Etot) {
  int i = blockIdx.x * 256 + threadIdx.x;
  if (i >= Etot) return;
  unsigned pp = epair[i];
  float x = LEAKY(al2[pp & 0xffffu].x + al2[pp >> 16].y);
  gw[i] = __expf(x);
}

// ---------------- aggregation: one edge per wave-instruction ----------------

// layer 1: 64 lanes x 1 dword = one 256B row per instruction; lane owns ch
// (2*lane, 2*lane+1); head = lane>>5. p via readlane -> SGPR base (saddr).
__global__ __launch_bounds__(256) void agg1_kernel(const unsigned short* __restrict__ Hb,
                                                   const float* __restrict__ gwa,
                                                   const float* __restrict__ gwb,
                                                   const unsigned* __restrict__ epair,
                                                   const int* __restrict__ off,
                                                   const float* __restrict__ b1,
                                                   float* __restrict__ O, int n) {
  int wid = (blockIdx.x * 256 + threadIdx.x) >> 6;
  int lane = threadIdx.x & 63;
  if (wid >= n) return;
  wid = __builtin_amdgcn_readfirstlane(wid);
  int half = lane >> 5;
  int k0 = off[wid], k1 = off[wid + 1];
  const unsigned* Hd = (const unsigned*)Hb;  // 64 dwords per row
  const float* gwp = half ? gwb : gwa;
  int j8 = lane & 7;

  float ax = 0.f, ay = 0.f, den = 0.f;
  int nb = (k1 - k0) >> 3;   // full batches of 8 edges
  int k = k0;
  unsigned pv = 0;
  float wv = 0.f;
  if (nb > 0) { pv = epair[k + j8]; wv = gwp[k + j8]; }
  for (int b = 0; b < nb; ++b) {
    unsigned pvc = pv;
    float wvc = wv;
    k += 8;
    if (b + 1 < nb) { pv = epair[k + j8]; wv = gwp[k + j8]; }
#pragma unroll
    for (int j = 0; j < 8; ++j) {
      unsigned p = ((unsigned)__builtin_amdgcn_readlane((int)pvc, j)) & 0xffffu;
      float w = __shfl(wvc, j, 8);            // static width-8 swizzle, per-head plane
      unsigned hv = Hd[(p << 6) + (unsigned)lane];
      den += w;
      union { unsigned u; __half2 h; } cv;
      cv.u = hv;
      ax = fmaf(__low2float(cv.h), w, ax);
      ay = fmaf(__high2float(cv.h), w, ay);
    }
  }
  for (int e = k; e < k1; ++e) {             // tail, one edge at a time (uniform)
    unsigned p = epair[e] & 0xffffu;
    float w = gwp[e];
    unsigned hv = Hd[(p << 6) + (unsigned)lane];
    den += w;
    union { unsigned u; __half2 h; } cv;
    cv.u = hv;
    ax = fmaf(__low2float(cv.h), w, ax);
    ay = fmaf(__high2float(cv.h), w, ay);
  }

  // every lane already holds the full den for its head; no reduction needed.
  float inv = 1.f / (den + 1e-16f);
  float2 bv = ((const float2*)b1)[lane];
  float r0 = ax * inv + bv.x;
  float r1 = ay * inv + bv.y;
  r0 = r0 > 0.f ? r0 : (__expf(r0) - 1.f);
  r1 = r1 > 0.f ? r1 : (__expf(r1) - 1.f);
  ((float2*)(O + ((size_t)wid << 7)))[lane] = make_float2(r0, r1);
}

// layer 2 + head: 2 edges per instruction (lanes 0-31 edge j, 32-63 edge j+1,
// each lane a dword = 2 ch of the 64); one xor-32 combine at the end.
__global__ __launch_bounds__(256) void agg2_kernel(const unsigned short* __restrict__ Hb2,
                                                   const float* __restrict__ gw,
                                                   const unsigned* __restrict__ epair,
                                                   const int* __restrict__ off,
                                                   const float* __restrict__ b2,
                                                   const float* __restrict__ lin_w,
                                                   const float* __restrict__ lin_b,
                                                   float* __restrict__ out, int n) {
  int wid = (blockIdx.x * 256 + threadIdx.x) >> 6;
  int lane = threadIdx.x & 63;
  if (wid >= n) return;
  wid = __builtin_amdgcn_readfirstlane(wid);
  int sel = lane >> 5;    // which edge of the pair this lane handles
  int c31 = lane & 31;    // dword (2 ch) within the row
  int k0 = off[wid], k1 = off[wid + 1];
  const unsigned* Hd = (const unsigned*)Hb2;  // 32 dwords per row
  int j8 = lane & 7;

  float ax = 0.f, ay = 0.f, den = 0.f;
  int nb = (k1 - k0) >> 3;
  int k = k0;
  unsigned pv = 0;
  float wv = 0.f;
  if (nb > 0) { pv = epair[k + j8]; wv = gw[k + j8]; }
  for (int b = 0; b < nb; ++b) {
    unsigned pvc = pv;
    float wvc = wv;
    k += 8;
    if (b + 1 < nb) { pv = epair[k + j8]; wv = gw[k + j8]; }
#pragma unroll
    for (int j = 0; j < 8; j += 2) {
      unsigned p2 = (unsigned)__shfl((int)pvc, j + sel, 8) & 0xffffu;
      float w = __shfl(wvc, j + sel, 8);
      unsigned hv = Hd[p2 * 32u + (unsigned)c31];
      den += w;
      union { unsigned u; __half2 h; } cv;
      cv.u = hv;
      ax = fmaf(__low2float(cv.h), w, ax);
      ay = fmaf(__high2float(cv.h), w, ay);
    }
  }
  for (int e = k; e < k1; ++e) {   // tail: whole wave on one edge; hi half zeroed
    unsigned p = epair[e] & 0xffffu;
    float wl = gw[e];
    float w = sel ? 0.f : wl;
    unsigned hv = Hd[p * 32u + (unsigned)c31];
    den += w;
    union { unsigned u; __half2 h; } cv;
    cv.u = hv;
    ax = fmaf(__low2float(cv.h), w, ax);
    ay = fmaf(__high2float(cv.h), w, ay);
  }

  ax += __shfl_xor(ax, 32, 64);
  ay += __shfl_xor(ay, 32, 64);
  den += __shfl_xor(den, 32, 64);
  float inv = 1.f / (den + 1e-16f);
  float2 bv = ((const float2*)b2)[c31];
  float2 lv = ((const float2*)lin_w)[c31];
  float p = (ax * inv + bv.x) * lv.x + (ay * inv + bv.y) * lv.y;
#pragma unroll
  for (int m = 1; m <= 16; m <<= 1) p += __shfl_xor(p, m, 64);
  if (lane == 0) out[wid] = p + lin_b[0];
}

// ---------------- launcher ----------------

static inline size_t alignup(size_t v) { return (v + 255) & ~(size_t)255; }

extern "C" void kernel_launch(void* const* d_in, const int* in_sizes, int n_in,
                              void* d_out, int out_size, void* d_ws, size_t ws_size,
                              hipStream_t stream) {
  const float* x   = (const float*)d_in[0];
  const int*   ei  = (const int*)d_in[1];
  const float* W1  = (const float*)d_in[2];
  const float* as1 = (const float*)d_in[3];
  const float* ad1 = (const float*)d_in[4];
  const float* b1  = (const float*)d_in[5];
  const float* W2  = (const float*)d_in[6];
  const float* as2 = (const float*)d_in[7];
  const float* ad2 = (const float*)d_in[8];
  const float* b2  = (const float*)d_in[9];
  const float* lw  = (const float*)d_in[10];
  const float* lb  = (const float*)d_in[11];
  float* out = (float*)d_out;

  const int N = out_size;          // 50000
  const int E = in_sizes[1] / 2;   // 1600000
  const int Etot = E + N;
  const int B = (N + 255) >> 8;    // 196 buckets

  char* p = (char*)d_ws;
  int* bcnt = (int*)p;  p += alignup((size_t)(B + 1) * 4);
  int* boff = (int*)p;  p += alignup((size_t)(B + 1) * 4);
  int* bcur = (int*)p;  p += alignup((size_t)B * 4);
  unsigned* entries = (unsigned*)p; p += alignup((size_t)Etot * 4);
  int* off  = (int*)p;  p += alignup((size_t)(N + 1) * 4);
  unsigned* epair = (unsigned*)p; p += alignup((size_t)Etot * 4);
  float2* als = (float2*)p; p += alignup((size_t)N * 8);
  float2* ald = (float2*)p; p += alignup((size_t)N * 8);
  float2* al2 = (float2*)p; p += alignup((size_t)N * 8);
  float* h1a  = (float*)p; p += alignup((size_t)N * 128 * 4);
  unsigned short* h1b = (unsigned short*)p; p += alignup((size_t)N * 128 * 2);
  unsigned short* h2b = (unsigned short*)p; p += alignup((size_t)N * 64 * 2);
  float* gw1a = (float*)p; p += alignup((size_t)Etot * 4);
  float* gw1b = (float*)p; p += alignup((size_t)Etot * 4);
  float* gw2  = (float*)entries;   // entries dead after csr_build

  hipMemsetAsync(bcnt, 0, (size_t)(B + 1) * sizeof(int), stream);

  constexpr int VPT = 8;
  int egrid = (Etot + 256 * VPT - 1) / (256 * VPT);
  int ewgrid = (Etot + 255) / 256;

  bucket_cnt_kernel<VPT><<<egrid, 256, 0, stream>>>(ei, E, N, bcnt);
  bucket_scan_kernel<<<1, 256, 0, stream>>>(bcnt, boff, bcur, B, off, N, Etot);
  bucket_scatter_kernel<VPT><<<egrid, 256, 0, stream>>>(ei, E, N, bcur, entries);
  csr_build_kernel<<<B, 256, 0, stream>>>(entries, boff, off, epair, N);

  gemm_logits_kernel<128, 128, 32, 2>
      <<<(N + 31) / 32, 256, 0, stream>>>(x, W1, as1, ad1, h1b, als, ald, N);
  ew1_kernel<<<ewgrid, 256, 0, stream>>>(epair, als, ald, gw1a, gw1b, Etot);
  agg1_kernel<<<(N + 3) / 4, 256, 0, stream>>>(h1b, gw1a, gw1b, epair, off, b1, h1a, N);

  gemm_logits_kernel<128, 64, 64, 1>
      <<<(N + 63) / 64, 256, 0, stream>>>(h1a, W2, as2, ad2, h2b, al2, nullptr, N);
  ew2_kernel<<<ewgrid, 256, 0, stream>>>(epair, al2, gw2, Etot);
  agg2_kernel<<<(N + 3) / 4, 256, 0, stream>>>(h2b, gw2, epair, off, b2, lw, lb, out, N);
}

// Round 6
// 218.422 us; speedup vs baseline: 1.1339x; 1.1339x over previous
//
#include <hip/hip_runtime.h>
#include <hip/hip_fp16.h>

// GAT regression: 2-layer GAT + linear head.
// R13: agg1 is L2-MISS-TRAFFIC bound (4 schedules all ~55us, FETCH ~165MB
//      invariant). So: (1) H1 rows stored fp8 e4m3 via HW cvt_pk (256->128B,
//      halves gather bytes; error attenuated ~1e-4 by two aggregations);
//      (2) ew1/ew2 deleted — weights computed in-agg per 64-edge superchunk
//      (one edge per lane, 2 exp/edge), staged in 2KB/wave LDS, read back
//      with broadcast ds_read; p via readlane -> wave-uniform saddr gathers.
//      H2 stays f16 (error budget), agg2 single-head: w via readlane (SGPR).
// Requires N < 65536 (16-bit packing). N = 50000.

#define LEAKY(x) ((x) > 0.f ? (x) : 0.2f * (x))

typedef float v2f __attribute__((ext_vector_type(2)));

__device__ inline unsigned h16pack(float a, float b) {
  union { __half h[2]; unsigned u; } cv;
  cv.h[0] = __float2half(a);
  cv.h[1] = __float2half(b);
  return cv.u;
}

// ---------------- bucketed CSR build ----------------

template <int VPT>
__global__ __launch_bounds__(256) void bucket_cnt_kernel(const int* __restrict__ ei, int E, int n,
                                                         int* __restrict__ bc) {
  __shared__ int lc[256];
  int t = threadIdx.x;
  lc[t] = 0;
  __syncthreads();
  int base = blockIdx.x * (256 * VPT) + t;
  int tot = E + n;
#pragma unroll
  for (int u = 0; u < VPT; ++u) {
    int i = base + u * 256;
    if (i < tot) {
      int d = (i < E) ? ei[E + i] : (i - E);
      atomicAdd(&lc[d >> 8], 1);
    }
  }
  __syncthreads();
  if (lc[t]) atomicAdd(&bc[t], lc[t]);
}

__global__ __launch_bounds__(256) void bucket_scan_kernel(const int* __restrict__ bc,
                                                          int* __restrict__ boff,
                                                          int* __restrict__ bcur, int B,
                                                          int* __restrict__ off, int n, int Etot) {
  __shared__ int sm[256];
  int t = threadIdx.x;
  int v = (t < B) ? bc[t] : 0;
  sm[t] = v;
  __syncthreads();
  for (int s = 1; s < 256; s <<= 1) {
    int a = (t >= s) ? sm[t - s] : 0;
    __syncthreads();
    sm[t] += a;
    __syncthreads();
  }
  int excl = sm[t] - v;
  if (t < B) { boff[t] = excl; bcur[t] = excl; }
  if (t == 0) { boff[B] = Etot; off[n] = Etot; }
}

template <int VPT>
__global__ __launch_bounds__(256) void bucket_scatter_kernel(const int* __restrict__ ei, int E,
                                                             int n, int* __restrict__ bcur,
                                                             unsigned* __restrict__ entries) {
  __shared__ int lc[256];
  __shared__ int lbase[256];
  int t = threadIdx.x;
  lc[t] = 0;
  __syncthreads();
  int base = blockIdx.x * (256 * VPT) + t;
  int tot = E + n;
  int bb[VPT], ll[VPT];
  unsigned pk[VPT];
#pragma unroll
  for (int u = 0; u < VPT; ++u) {
    int i = base + u * 256;
    bb[u] = -1;
    if (i < tot) {
      int s, d;
      if (i < E) { s = ei[i]; d = ei[E + i]; }
      else       { s = d = i - E; }
      int b = d >> 8;
      bb[u] = b;
      ll[u] = atomicAdd(&lc[b], 1);
      pk[u] = (unsigned)s | ((unsigned)(d & 255) << 16);
    }
  }
  __syncthreads();
  if (lc[t]) lbase[t] = atomicAdd(&bcur[t], lc[t]);
  __syncthreads();
#pragma unroll
  for (int u = 0; u < VPT; ++u)
    if (bb[u] >= 0) entries[lbase[bb[u]] + ll[u]] = pk[u];
}

__global__ __launch_bounds__(256) void csr_build_kernel(const unsigned* __restrict__ entries,
                                                        const int* __restrict__ boff,
                                                        int* __restrict__ off,
                                                        unsigned* __restrict__ epair, int n) {
  __shared__ int hist[256];
  __shared__ int scn[256];
  __shared__ int cur[256];
  int b = blockIdx.x, t = threadIdx.x;
  int k0 = boff[b], k1 = boff[b + 1];
  hist[t] = 0;
  __syncthreads();
  for (int k = k0 + t; k < k1; k += 256) atomicAdd(&hist[(entries[k] >> 16) & 255], 1);
  __syncthreads();
  int v = hist[t];
  scn[t] = v;
  __syncthreads();
  for (int s = 1; s < 256; s <<= 1) {
    int a = (t >= s) ? scn[t - s] : 0;
    __syncthreads();
    scn[t] += a;
    __syncthreads();
  }
  int excl = scn[t] - v;
  int d = (b << 8) + t;
  if (d < n) off[d] = k0 + excl;
  cur[t] = k0 + excl;
  __syncthreads();
  unsigned dbase = (unsigned)(b << 8) << 16;
  for (int k = k0 + t; k < k1; k += 256) {
    unsigned e = entries[k];
    unsigned dl = (e >> 16) & 255;
    int p = atomicAdd(&cur[dl], 1);
    epair[p] = (e & 0xffffu) | (dbase + (dl << 16));
  }
}

// ---------------- fused GEMM + logits (W via L1/L2, X tile in LDS) -----------

template <int K, int M, int NODES, int HEADS, int FP8>
__global__ __launch_bounds__(256) void gemm_logits_kernel(const float* __restrict__ X,
                                                          const float* __restrict__ W,
                                                          const float* __restrict__ a_src,
                                                          const float* __restrict__ a_dst,
                                                          void* __restrict__ Hb,
                                                          float2* __restrict__ als,
                                                          float2* __restrict__ ald, int n) {
  constexpr int JPER = 4;
  constexpr int NSLOT = M / JPER;
  constexpr int SLOTS = 256 / NSLOT;
  constexpr int PER = NODES / SLOTS;
  __shared__ float Xl[NODES * K];

  int t = threadIdx.x;
  int nb0 = blockIdx.x * NODES;

  for (int i = t; i < NODES * K / 4; i += 256) {
    int r = i / (K / 4);
    int c = i % (K / 4);
    int node = nb0 + r;
    int nc = node < n ? node : (n - 1);
    ((float4*)Xl)[i] = ((const float4*)(X + (size_t)nc * K))[c];
  }
  __syncthreads();

  int j0 = (t % NSLOT) * JPER;
  int slot = t / NSLOT;
  const float4* Wg = (const float4*)W;

  float4 Asv = *(const float4*)(a_src + j0);
  float4 Adv = *(const float4*)(a_dst + j0);

  float acc[PER][JPER];
#pragma unroll
  for (int s = 0; s < PER; ++s)
#pragma unroll
    for (int q = 0; q < JPER; ++q) acc[s][q] = 0.f;

  for (int k4 = 0; k4 < K / 4; ++k4) {
    float4 w0 = Wg[(k4 * 4 + 0) * (M / 4) + (j0 >> 2)];
    float4 w1 = Wg[(k4 * 4 + 1) * (M / 4) + (j0 >> 2)];
    float4 w2 = Wg[(k4 * 4 + 2) * (M / 4) + (j0 >> 2)];
    float4 w3 = Wg[(k4 * 4 + 3) * (M / 4) + (j0 >> 2)];
#pragma unroll
    for (int s = 0; s < PER; ++s) {
      float4 xv = ((const float4*)Xl)[(slot * PER + s) * (K / 4) + k4];
      acc[s][0] += xv.x * w0.x + xv.y * w1.x + xv.z * w2.x + xv.w * w3.x;
      acc[s][1] += xv.x * w0.y + xv.y * w1.y + xv.z * w2.y + xv.w * w3.y;
      acc[s][2] += xv.x * w0.z + xv.y * w1.z + xv.z * w2.z + xv.w * w3.z;
      acc[s][3] += xv.x * w0.w + xv.y * w1.w + xv.z * w2.w + xv.w * w3.w;
    }
  }

#pragma unroll
  for (int s = 0; s < PER; ++s) {
    int node = nb0 + slot * PER + s;
    if (node < n) {
      if constexpr (FP8) {
        int v = __builtin_amdgcn_cvt_pk_fp8_f32(acc[s][0], acc[s][1], 0, false);
        v = __builtin_amdgcn_cvt_pk_fp8_f32(acc[s][2], acc[s][3], v, true);
        *(unsigned*)((unsigned char*)Hb + (size_t)node * M + j0) = (unsigned)v;
      } else {
        uint2 b;
        b.x = h16pack(acc[s][0], acc[s][1]);
        b.y = h16pack(acc[s][2], acc[s][3]);
        *(uint2*)((unsigned short*)Hb + (size_t)node * M + j0) = b;
      }
    }
    float ps = acc[s][0] * Asv.x + acc[s][1] * Asv.y + acc[s][2] * Asv.z + acc[s][3] * Asv.w;
    float pd = acc[s][0] * Adv.x + acc[s][1] * Adv.y + acc[s][2] * Adv.z + acc[s][3] * Adv.w;
#pragma unroll
    for (int m = 1; m <= 8; m <<= 1) {
      ps += __shfl_xor(ps, m, 64);
      pd += __shfl_xor(pd, m, 64);
    }
    if (HEADS == 2) {
      float ps_o = __shfl_xor(ps, 16, 64);
      float pd_o = __shfl_xor(pd, 16, 64);
      if ((t & 31) == 0 && node < n) {
        als[node] = make_float2(ps, ps_o);
        ald[node] = make_float2(pd, pd_o);
      }
    } else {
      if ((t & 15) == 0 && node < n) als[node] = make_float2(ps, pd);
    }
  }
}

// ---------------- aggregation ----------------

// layer 1 (fp8 rows, 128B): superchunk of 64 edges; weight phase = 1 edge/lane
// (2 exp), weights staged in per-wave LDS; FMA loop: readlane(p) -> saddr
// ushort load (2 fp8 ch/lane), broadcast ds_read(w), cvt_pk_f32_fp8, 2 fma.
__global__ __launch_bounds__(256) void agg1_kernel(const unsigned char* __restrict__ Hb8,
                                                   const float2* __restrict__ als,
                                                   const float2* __restrict__ ald,
                                                   const unsigned* __restrict__ epair,
                                                   const int* __restrict__ off,
                                                   const float* __restrict__ b1,
                                                   float* __restrict__ O, int n) {
  __shared__ float wlds[4][128];
  int wid = (blockIdx.x * 256 + threadIdx.x) >> 6;
  int lane = threadIdx.x & 63;
  if (wid >= n) return;
  wid = __builtin_amdgcn_readfirstlane(wid);
  int wslot = (threadIdx.x >> 6) & 3;
  int half = lane >> 5;                       // head of ch (2*lane, 2*lane+1)
  int k0 = off[wid], k1 = off[wid + 1];
  const unsigned short* Hu = (const unsigned short*)Hb8;  // row = 64 ushort
  float2 advv = ald[wid];
  float* wrow = &wlds[wslot][half << 6];

  float ax = 0.f, ay = 0.f, den = 0.f;

  for (int kb = k0; kb < k1; kb += 64) {
    int rem = min(k1 - kb, 64);
    // ---- weight phase: one edge per lane ----
    int e = kb + (lane < rem ? lane : rem - 1);
    unsigned pp = epair[e];
    float2 l = als[pp & 0xffffu];
    float g0 = __expf(LEAKY(l.x + advv.x));
    float g1 = __expf(LEAKY(l.y + advv.y));
    wlds[wslot][lane] = g0;
    wlds[wslot][64 + lane] = g1;

#define EDGE1(jj)                                                                   \
  {                                                                                 \
    unsigned p = ((unsigned)__builtin_amdgcn_readlane((int)pp, (jj))) & 0xffffu;    \
    float w = wrow[(jj)];                                                           \
    unsigned short hv = Hu[(p << 6) | (unsigned)lane];                              \
    v2f hf = __builtin_amdgcn_cvt_pk_f32_fp8((int)hv, false);                       \
    den += w;                                                                       \
    ax = fmaf(hf.x, w, ax);                                                         \
    ay = fmaf(hf.y, w, ay);                                                         \
  }

    int nb = rem >> 3;
    for (int b = 0; b < nb; ++b) {
      int jb = b << 3;
#pragma unroll
      for (int j = 0; j < 8; ++j) EDGE1(jb + j);
    }
    for (int jj = nb << 3; jj < rem; ++jj) EDGE1(jj);
#undef EDGE1
  }

  // every lane holds the full den of its head; no reduction needed.
  float inv = 1.f / (den + 1e-16f);
  float2 bv = ((const float2*)b1)[lane];
  float r0 = ax * inv + bv.x;
  float r1 = ay * inv + bv.y;
  r0 = r0 > 0.f ? r0 : (__expf(r0) - 1.f);
  r1 = r1 > 0.f ? r1 : (__expf(r1) - 1.f);
  ((float2*)(O + ((size_t)wid << 7)))[lane] = make_float2(r0, r1);
}

// layer 2 + head (f16 rows, 128B): single head -> w stays scalar via readlane,
// no LDS, no den reduction; lane owns 1 channel; 6-shfl head reduce at end.
__global__ __launch_bounds__(256) void agg2_kernel(const unsigned short* __restrict__ Hb2,
                                                   const float2* __restrict__ al2,
                                                   const unsigned* __restrict__ epair,
                                                   const int* __restrict__ off,
                                                   const float* __restrict__ b2,
                                                   const float* __restrict__ lin_w,
                                                   const float* __restrict__ lin_b,
                                                   float* __restrict__ out, int n) {
  int wid = (blockIdx.x * 256 + threadIdx.x) >> 6;
  int lane = threadIdx.x & 63;
  if (wid >= n) return;
  wid = __builtin_amdgcn_readfirstlane(wid);
  int k0 = off[wid], k1 = off[wid + 1];
  float adv = al2[wid].y;

  float a = 0.f, den = 0.f;

  for (int kb = k0; kb < k1; kb += 64) {
    int rem = min(k1 - kb, 64);
    int e = kb + (lane < rem ? lane : rem - 1);
    unsigned pp = epair[e];
    float g = __expf(LEAKY(al2[pp & 0xffffu].x + adv));

#define EDGE2(jj)                                                                   \
  {                                                                                 \
    unsigned p = ((unsigned)__builtin_amdgcn_readlane((int)pp, (jj))) & 0xffffu;    \
    float w = __int_as_float(__builtin_amdgcn_readlane(__float_as_int(g), (jj)));   \
    unsigned short hv = Hb2[(p << 6) | (unsigned)lane];                             \
    union { unsigned short u; __half h; } cv;                                       \
    cv.u = hv;                                                                      \
    den += w;                                                                       \
    a = fmaf(__half2float(cv.h), w, a);                                             \
  }

    int nb = rem >> 3;
    for (int b = 0; b < nb; ++b) {
      int jb = b << 3;
#pragma unroll
      for (int j = 0; j < 8; ++j) EDGE2(jb + j);
    }
    for (int jj = nb << 3; jj < rem; ++jj) EDGE2(jj);
#undef EDGE2
  }

  float inv = 1.f / (den + 1e-16f);
  float r = a * inv + b2[lane];
  float p = r * lin_w[lane];
#pragma unroll
  for (int m = 1; m <= 32; m <<= 1) p += __shfl_xor(p, m, 64);
  if (lane == 0) out[wid] = p + lin_b[0];
}

// ---------------- launcher ----------------

static inline size_t alignup(size_t v) { return (v + 255) & ~(size_t)255; }

extern "C" void kernel_launch(void* const* d_in, const int* in_sizes, int n_in,
                              void* d_out, int out_size, void* d_ws, size_t ws_size,
                              hipStream_t stream) {
  const float* x   = (const float*)d_in[0];
  const int*   ei  = (const int*)d_in[1];
  const float* W1  = (const float*)d_in[2];
  const float* as1 = (const float*)d_in[3];
  const float* ad1 = (const float*)d_in[4];
  const float* b1  = (const float*)d_in[5];
  const float* W2  = (const float*)d_in[6];
  const float* as2 = (const float*)d_in[7];
  const float* ad2 = (const float*)d_in[8];
  const float* b2  = (const float*)d_in[9];
  const float* lw  = (const float*)d_in[10];
  const float* lb  = (const float*)d_in[11];
  float* out = (float*)d_out;

  const int N = out_size;          // 50000
  const int E = in_sizes[1] / 2;   // 1600000
  const int Etot = E + N;
  const int B = (N + 255) >> 8;    // 196 buckets

  char* p = (char*)d_ws;
  int* bcnt = (int*)p;  p += alignup((size_t)(B + 1) * 4);
  int* boff = (int*)p;  p += alignup((size_t)(B + 1) * 4);
  int* bcur = (int*)p;  p += alignup((size_t)B * 4);
  unsigned* entries = (unsigned*)p; p += alignup((size_t)Etot * 4);
  int* off  = (int*)p;  p += alignup((size_t)(N + 1) * 4);
  unsigned* epair = (unsigned*)p; p += alignup((size_t)Etot * 4);
  float2* als = (float2*)p; p += alignup((size_t)N * 8);
  float2* ald = (float2*)p; p += alignup((size_t)N * 8);
  float2* al2 = (float2*)p; p += alignup((size_t)N * 8);
  float* h1a  = (float*)p; p += alignup((size_t)N * 128 * 4);
  unsigned char*  h1b = (unsigned char*)p;  p += alignup((size_t)N * 128);
  unsigned short* h2b = (unsigned short*)p; p += alignup((size_t)N * 64 * 2);

  hipMemsetAsync(bcnt, 0, (size_t)(B + 1) * sizeof(int), stream);

  constexpr int VPT = 8;
  int egrid = (Etot + 256 * VPT - 1) / (256 * VPT);

  bucket_cnt_kernel<VPT><<<egrid, 256, 0, stream>>>(ei, E, N, bcnt);
  bucket_scan_kernel<<<1, 256, 0, stream>>>(bcnt, boff, bcur, B, off, N, Etot);
  bucket_scatter_kernel<VPT><<<egrid, 256, 0, stream>>>(ei, E, N, bcur, entries);
  csr_build_kernel<<<B, 256, 0, stream>>>(entries, boff, off, epair, N);

  gemm_logits_kernel<128, 128, 32, 2, 1>
      <<<(N + 31) / 32, 256, 0, stream>>>(x, W1, as1, ad1, (void*)h1b, als, ald, N);
  agg1_kernel<<<(N + 3) / 4, 256, 0, stream>>>(h1b, als, ald, epair, off, b1, h1a, N);

  gemm_logits_kernel<128, 64, 64, 1, 0>
      <<<(N + 63) / 64, 256, 0, stream>>>(h1a, W2, as2, ad2, (void*)h2b, al2, nullptr, N);
  agg2_kernel<<<(N + 3) / 4, 256, 0, stream>>>(h2b, al2, epair, off, b2, lw, lb, out, N);
}

// Round 8
// 184.415 us; speedup vs baseline: 1.3430x; 1.1844x over previous
//
#include <hip/hip_runtime.h>
#include <hip/hip_fp16.h>

// GAT regression: 2-layer GAT + linear head.
// R15 (= R14 + compile fix: cvt_pkrtz returns __fp16x2, not _Float16x2):
// gemm_logits replaced by MFMA (v_mfma_f32_16x16x32_f16, f32 accum):
//  - A-frags loaded per-lane directly from global f32 rows (2 float4 + pkrtz
//    per kk; row = lane&15, k = (lane>>4)*8+i  [AMD layout]).
//  - B-frags from wprep-packed f16 W in fragment order: one fully-coalesced
//    1KB uint4 load per (cn,kk); W packs are 32/16 KB, L1-resident.
//  - C/D: col=lane&15, row=(lane>>4)*4+reg [verified layout]; logits via
//    4-shfl c-reduce; H1 stored fp8 e4m3, H2 f16 (as R13).
// R13 retained: fp8 H1 rows (halved agg1 gather bytes), in-agg weights via
// per-wave LDS staging, wave-uniform saddr row gathers.
// Requires N < 65536 (16-bit packing). N = 50000.

#define LEAKY(x) ((x) > 0.f ? (x) : 0.2f * (x))

typedef float v2f __attribute__((ext_vector_type(2)));
typedef _Float16 f16x8 __attribute__((ext_vector_type(8)));
typedef __fp16 h16x2 __attribute__((ext_vector_type(2)));
typedef float f32x4 __attribute__((ext_vector_type(4)));

// ---------------- bucketed CSR build ----------------

template <int VPT>
__global__ __launch_bounds__(256) void bucket_cnt_kernel(const int* __restrict__ ei, int E, int n,
                                                         int* __restrict__ bc) {
  __shared__ int lc[256];
  int t = threadIdx.x;
  lc[t] = 0;
  __syncthreads();
  int base = blockIdx.x * (256 * VPT) + t;
  int tot = E + n;
#pragma unroll
  for (int u = 0; u < VPT; ++u) {
    int i = base + u * 256;
    if (i < tot) {
      int d = (i < E) ? ei[E + i] : (i - E);
      atomicAdd(&lc[d >> 8], 1);
    }
  }
  __syncthreads();
  if (lc[t]) atomicAdd(&bc[t], lc[t]);
}

__global__ __launch_bounds__(256) void bucket_scan_kernel(const int* __restrict__ bc,
                                                          int* __restrict__ boff,
                                                          int* __restrict__ bcur, int B,
                                                          int* __restrict__ off, int n, int Etot) {
  __shared__ int sm[256];
  int t = threadIdx.x;
  int v = (t < B) ? bc[t] : 0;
  sm[t] = v;
  __syncthreads();
  for (int s = 1; s < 256; s <<= 1) {
    int a = (t >= s) ? sm[t - s] : 0;
    __syncthreads();
    sm[t] += a;
    __syncthreads();
  }
  int excl = sm[t] - v;
  if (t < B) { boff[t] = excl; bcur[t] = excl; }
  if (t == 0) { boff[B] = Etot; off[n] = Etot; }
}

template <int VPT>
__global__ __launch_bounds__(256) void bucket_scatter_kernel(const int* __restrict__ ei, int E,
                                                             int n, int* __restrict__ bcur,
                                                             unsigned* __restrict__ entries) {
  __shared__ int lc[256];
  __shared__ int lbase[256];
  int t = threadIdx.x;
  lc[t] = 0;
  __syncthreads();
  int base = blockIdx.x * (256 * VPT) + t;
  int tot = E + n;
  int bb[VPT], ll[VPT];
  unsigned pk[VPT];
#pragma unroll
  for (int u = 0; u < VPT; ++u) {
    int i = base + u * 256;
    bb[u] = -1;
    if (i < tot) {
      int s, d;
      if (i < E) { s = ei[i]; d = ei[E + i]; }
      else       { s = d = i - E; }
      int b = d >> 8;
      bb[u] = b;
      ll[u] = atomicAdd(&lc[b], 1);
      pk[u] = (unsigned)s | ((unsigned)(d & 255) << 16);
    }
  }
  __syncthreads();
  if (lc[t]) lbase[t] = atomicAdd(&bcur[t], lc[t]);
  __syncthreads();
#pragma unroll
  for (int u = 0; u < VPT; ++u)
    if (bb[u] >= 0) entries[lbase[bb[u]] + ll[u]] = pk[u];
}

__global__ __launch_bounds__(256) void csr_build_kernel(const unsigned* __restrict__ entries,
                                                        const int* __restrict__ boff,
                                                        int* __restrict__ off,
                                                        unsigned* __restrict__ epair, int n) {
  __shared__ int hist[256];
  __shared__ int scn[256];
  __shared__ int cur[256];
  int b = blockIdx.x, t = threadIdx.x;
  int k0 = boff[b], k1 = boff[b + 1];
  hist[t] = 0;
  __syncthreads();
  for (int k = k0 + t; k < k1; k += 256) atomicAdd(&hist[(entries[k] >> 16) & 255], 1);
  __syncthreads();
  int v = hist[t];
  scn[t] = v;
  __syncthreads();
  for (int s = 1; s < 256; s <<= 1) {
    int a = (t >= s) ? scn[t - s] : 0;
    __syncthreads();
    scn[t] += a;
    __syncthreads();
  }
  int excl = scn[t] - v;
  int d = (b << 8) + t;
  if (d < n) off[d] = k0 + excl;
  cur[t] = k0 + excl;
  __syncthreads();
  unsigned dbase = (unsigned)(b << 8) << 16;
  for (int k = k0 + t; k < k1; k += 256) {
    unsigned e = entries[k];
    unsigned dl = (e >> 16) & 255;
    int p = atomicAdd(&cur[dl], 1);
    epair[p] = (e & 0xffffu) | (dbase + (dl << 16));
  }
}

// ---------------- W fragment pre-pack (f32 -> f16, fragment order) ----------

// element e = (((cn*4+kk)*4+g)*16+c)*8+i  stores  W[kk*32+g*8+i][cn*16+c]
__global__ __launch_bounds__(256) void wprep_kernel(const float* __restrict__ W1,
                                                    const float* __restrict__ W2,
                                                    unsigned short* __restrict__ Wp1,
                                                    unsigned short* __restrict__ Wp2) {
  int t = blockIdx.x * 256 + threadIdx.x;
  bool second = t >= 16384;
  int e = second ? t - 16384 : t;
  if (second && e >= 8192) return;
  const float* W = second ? W2 : W1;
  unsigned short* Wp = second ? Wp2 : Wp1;
  int M = second ? 64 : 128;
  int i = e & 7;
  int c = (e >> 3) & 15;
  int g = (e >> 7) & 3;
  int kk = (e >> 9) & 3;
  int cn = e >> 11;
  int k = kk * 32 + g * 8 + i;
  int col = cn * 16 + c;
  __half h = __float2half(W[k * M + col]);
  Wp[e] = *(unsigned short*)&h;
}

// ---------------- MFMA GEMM + logits ----------------

// HEADS==2: block = 4 waves = 2M x 2N(head); 32 rows, N=128, H out fp8.
// HEADS==1: block = 4 waves = 4M; 64 rows, N=64, H out f16.
template <int HEADS>
__global__ __launch_bounds__(256) void gemm_mfma_kernel(const float* __restrict__ X,
                                                        const uint4* __restrict__ Wp,
                                                        const float* __restrict__ a_src,
                                                        const float* __restrict__ a_dst,
                                                        void* __restrict__ Hout,
                                                        float2* __restrict__ als,
                                                        float2* __restrict__ ald, int n) {
  constexpr int WM = (HEADS == 2) ? 2 : 4;
  constexpr int ROWS = WM * 16;
  __shared__ float lgt[2][2][2][16];  // [wm][head][src/dst][row] (HEADS==2 only)
  int t = threadIdx.x;
  int wave = t >> 6, lane = t & 63;
  int wm, wn;
  if (HEADS == 2) { wm = wave >> 1; wn = wave & 1; } else { wm = wave; wn = 0; }
  int g = lane >> 4, c = lane & 15;
  int nb0 = blockIdx.x * ROWS;

  // ---- A fragments: row = lane&15, k = (lane>>4)*8 + i (+32*kk) ----
  int arow = nb0 + wm * 16 + c;
  int arc = arow < n ? arow : (n - 1);
  const float* xr = X + (size_t)arc * 128 + g * 8;
  f16x8 af[4];
#pragma unroll
  for (int kk = 0; kk < 4; ++kk) {
    float4 x0 = *(const float4*)(xr + kk * 32);
    float4 x1 = *(const float4*)(xr + kk * 32 + 4);
    union { f16x8 v; h16x2 p[4]; } A;
    A.p[0] = __builtin_amdgcn_cvt_pkrtz(x0.x, x0.y);
    A.p[1] = __builtin_amdgcn_cvt_pkrtz(x0.z, x0.w);
    A.p[2] = __builtin_amdgcn_cvt_pkrtz(x1.x, x1.y);
    A.p[3] = __builtin_amdgcn_cvt_pkrtz(x1.z, x1.w);
    af[kk] = A.v;
  }

  // ---- MFMA: 4 col-tiles x 4 k-steps ----
  f32x4 acc[4];
  f32x4 z = {0.f, 0.f, 0.f, 0.f};
#pragma unroll
  for (int cn = 0; cn < 4; ++cn) acc[cn] = z;
#pragma unroll
  for (int cn = 0; cn < 4; ++cn) {
    int cng = wn * 4 + cn;
#pragma unroll
    for (int kk = 0; kk < 4; ++kk) {
      union { uint4 u; f16x8 v; } B;
      B.u = Wp[(cng * 4 + kk) * 64 + lane];
      acc[cn] = __builtin_amdgcn_mfma_f32_16x16x32_f16(af[kk], B.v, acc[cn], 0, 0, 0);
    }
  }

  // ---- epilogue: H store + logits ----
  float asv[4], adv[4];
#pragma unroll
  for (int cn = 0; cn < 4; ++cn) {
    int col_l = wn * 64 + cn * 16 + c;
    asv[cn] = a_src[col_l];
    adv[cn] = a_dst[col_l];
  }
  float ps[4] = {0.f, 0.f, 0.f, 0.f};
  float pd[4] = {0.f, 0.f, 0.f, 0.f};
#pragma unroll
  for (int cn = 0; cn < 4; ++cn) {
#pragma unroll
    for (int r = 0; r < 4; ++r) {
      float v = acc[cn][r];
      ps[r] = fmaf(v, asv[cn], ps[r]);
      pd[r] = fmaf(v, adv[cn], pd[r]);
      int noder = nb0 + wm * 16 + g * 4 + r;
      int colg = wn * 64 + cn * 16 + c;
      if (noder < n) {
        if constexpr (HEADS == 2) {
          int b8 = __builtin_amdgcn_cvt_pk_fp8_f32(v, v, 0, false);
          ((unsigned char*)Hout)[(size_t)noder * 128 + colg] = (unsigned char)(b8 & 0xff);
        } else {
          __half hh = __float2half(v);
          ((unsigned short*)Hout)[(size_t)noder * 64 + colg] = *(unsigned short*)&hh;
        }
      }
    }
  }
#pragma unroll
  for (int r = 0; r < 4; ++r) {
#pragma unroll
    for (int m = 1; m <= 8; m <<= 1) {
      ps[r] += __shfl_xor(ps[r], m, 64);
      pd[r] += __shfl_xor(pd[r], m, 64);
    }
  }
  if constexpr (HEADS == 2) {
    if (c == 0) {
#pragma unroll
      for (int r = 0; r < 4; ++r) {
        lgt[wm][wn][0][g * 4 + r] = ps[r];
        lgt[wm][wn][1][g * 4 + r] = pd[r];
      }
    }
    __syncthreads();
    if (t < 32) {
      int wmm = t >> 4, row = t & 15;
      int node = nb0 + wmm * 16 + row;
      if (node < n) {
        als[node] = make_float2(lgt[wmm][0][0][row], lgt[wmm][1][0][row]);
        ald[node] = make_float2(lgt[wmm][0][1][row], lgt[wmm][1][1][row]);
      }
    }
  } else {
    if (c == 0) {
#pragma unroll
      for (int r = 0; r < 4; ++r) {
        int node = nb0 + wm * 16 + g * 4 + r;
        if (node < n) als[node] = make_float2(ps[r], pd[r]);
      }
    }
  }
}

// ---------------- aggregation (R13, unchanged) ----------------

__global__ __launch_bounds__(256) void agg1_kernel(const unsigned char* __restrict__ Hb8,
                                                   const float2* __restrict__ als,
                                                   const float2* __restrict__ ald,
                                                   const unsigned* __restrict__ epair,
                                                   const int* __restrict__ off,
                                                   const float* __restrict__ b1,
                                                   float* __restrict__ O, int n) {
  __shared__ float wlds[4][128];
  int wid = (blockIdx.x * 256 + threadIdx.x) >> 6;
  int lane = threadIdx.x & 63;
  if (wid >= n) return;
  wid = __builtin_amdgcn_readfirstlane(wid);
  int wslot = (threadIdx.x >> 6) & 3;
  int half = lane >> 5;
  int k0 = off[wid], k1 = off[wid + 1];
  const unsigned short* Hu = (const unsigned short*)Hb8;
  float2 advv = ald[wid];
  float* wrow = &wlds[wslot][half << 6];

  float ax = 0.f, ay = 0.f, den = 0.f;

  for (int kb = k0; kb < k1; kb += 64) {
    int rem = min(k1 - kb, 64);
    int e = kb + (lane < rem ? lane : rem - 1);
    unsigned pp = epair[e];
    float2 l = als[pp & 0xffffu];
    float g0 = __expf(LEAKY(l.x + advv.x));
    float g1 = __expf(LEAKY(l.y + advv.y));
    wlds[wslot][lane] = g0;
    wlds[wslot][64 + lane] = g1;

#define EDGE1(jj)                                                                   \
  {                                                                                 \
    unsigned p = ((unsigned)__builtin_amdgcn_readlane((int)pp, (jj))) & 0xffffu;    \
    float w = wrow[(jj)];                                                           \
    unsigned short hv = Hu[(p << 6) | (unsigned)lane];                              \
    v2f hf = __builtin_amdgcn_cvt_pk_f32_fp8((int)hv, false);                       \
    den += w;                                                                       \
    ax = fmaf(hf.x, w, ax);                                                         \
    ay = fmaf(hf.y, w, ay);                                                         \
  }

    int nb = rem >> 3;
    for (int b = 0; b < nb; ++b) {
      int jb = b << 3;
#pragma unroll
      for (int j = 0; j < 8; ++j) EDGE1(jb + j);
    }
    for (int jj = nb << 3; jj < rem; ++jj) EDGE1(jj);
#undef EDGE1
  }

  float inv = 1.f / (den + 1e-16f);
  float2 bv = ((const float2*)b1)[lane];
  float r0 = ax * inv + bv.x;
  float r1 = ay * inv + bv.y;
  r0 = r0 > 0.f ? r0 : (__expf(r0) - 1.f);
  r1 = r1 > 0.f ? r1 : (__expf(r1) - 1.f);
  ((float2*)(O + ((size_t)wid << 7)))[lane] = make_float2(r0, r1);
}

__global__ __launch_bounds__(256) void agg2_kernel(const unsigned short* __restrict__ Hb2,
                                                   const float2* __restrict__ al2,
                                                   const unsigned* __restrict__ epair,
                                                   const int* __restrict__ off,
                                                   const float* __restrict__ b2,
                                                   const float* __restrict__ lin_w,
                                                   const float* __restrict__ lin_b,
                                                   float* __restrict__ out, int n) {
  int wid = (blockIdx.x * 256 + threadIdx.x) >> 6;
  int lane = threadIdx.x & 63;
  if (wid >= n) return;
  wid = __builtin_amdgcn_readfirstlane(wid);
  int k0 = off[wid], k1 = off[wid + 1];
  float adv = al2[wid].y;

  float a = 0.f, den = 0.f;

  for (int kb = k0; kb < k1; kb += 64) {
    int rem = min(k1 - kb, 64);
    int e = kb + (lane < rem ? lane : rem - 1);
    unsigned pp = epair[e];
    float g = __expf(LEAKY(al2[pp & 0xffffu].x + adv));

#define EDGE2(jj)                                                                   \
  {                                                                                 \
    unsigned p = ((unsigned)__builtin_amdgcn_readlane((int)pp, (jj))) & 0xffffu;    \
    float w = __int_as_float(__builtin_amdgcn_readlane(__float_as_int(g), (jj)));   \
    unsigned short hv = Hb2[(p << 6) | (unsigned)lane];                             \
    union { unsigned short u; __half h; } cv;                                       \
    cv.u = hv;                                                                      \
    den += w;                                                                       \
    a = fmaf(__half2float(cv.h), w, a);                                             \
  }

    int nb = rem >> 3;
    for (int b = 0; b < nb; ++b) {
      int jb = b << 3;
#pragma unroll
      for (int j = 0; j < 8; ++j) EDGE2(jb + j);
    }
    for (int jj = nb << 3; jj < rem; ++jj) EDGE2(jj);
#undef EDGE2
  }

  float inv = 1.f / (den + 1e-16f);
  float r = a * inv + b2[lane];
  float p = r * lin_w[lane];
#pragma unroll
  for (int m = 1; m <= 32; m <<= 1) p += __shfl_xor(p, m, 64);
  if (lane == 0) out[wid] = p + lin_b[0];
}

// ---------------- launcher ----------------

static inline size_t alignup(size_t v) { return (v + 255) & ~(size_t)255; }

extern "C" void kernel_launch(void* const* d_in, const int* in_sizes, int n_in,
                              void* d_out, int out_size, void* d_ws, size_t ws_size,
                              hipStream_t stream) {
  const float* x   = (const float*)d_in[0];
  const int*   ei  = (const int*)d_in[1];
  const float* W1  = (const float*)d_in[2];
  const float* as1 = (const float*)d_in[3];
  const float* ad1 = (const float*)d_in[4];
  const float* b1  = (const float*)d_in[5];
  const float* W2  = (const float*)d_in[6];
  const float* as2 = (const float*)d_in[7];
  const float* ad2 = (const float*)d_in[8];
  const float* b2  = (const float*)d_in[9];
  const float* lw  = (const float*)d_in[10];
  const float* lb  = (const float*)d_in[11];
  float* out = (float*)d_out;

  const int N = out_size;          // 50000
  const int E = in_sizes[1] / 2;   // 1600000
  const int Etot = E + N;
  const int B = (N + 255) >> 8;    // 196 buckets

  char* p = (char*)d_ws;
  int* bcnt = (int*)p;  p += alignup((size_t)(B + 1) * 4);
  int* boff = (int*)p;  p += alignup((size_t)(B + 1) * 4);
  int* bcur = (int*)p;  p += alignup((size_t)B * 4);
  unsigned* entries = (unsigned*)p; p += alignup((size_t)Etot * 4);
  int* off  = (int*)p;  p += alignup((size_t)(N + 1) * 4);
  unsigned* epair = (unsigned*)p; p += alignup((size_t)Etot * 4);
  float2* als = (float2*)p; p += alignup((size_t)N * 8);
  float2* ald = (float2*)p; p += alignup((size_t)N * 8);
  float2* al2 = (float2*)p; p += alignup((size_t)N * 8);
  float* h1a  = (float*)p; p += alignup((size_t)N * 128 * 4);
  unsigned char*  h1b = (unsigned char*)p;  p += alignup((size_t)N * 128);
  unsigned short* h2b = (unsigned short*)p; p += alignup((size_t)N * 64 * 2);
  unsigned short* wp1 = (unsigned short*)p; p += alignup((size_t)16384 * 2);
  unsigned short* wp2 = (unsigned short*)p; p += alignup((size_t)8192 * 2);

  hipMemsetAsync(bcnt, 0, (size_t)(B + 1) * sizeof(int), stream);

  constexpr int VPT = 8;
  int egrid = (Etot + 256 * VPT - 1) / (256 * VPT);

  wprep_kernel<<<96, 256, 0, stream>>>(W1, W2, wp1, wp2);
  bucket_cnt_kernel<VPT><<<egrid, 256, 0, stream>>>(ei, E, N, bcnt);
  bucket_scan_kernel<<<1, 256, 0, stream>>>(bcnt, boff, bcur, B, off, N, Etot);
  bucket_scatter_kernel<VPT><<<egrid, 256, 0, stream>>>(ei, E, N, bcur, entries);
  csr_build_kernel<<<B, 256, 0, stream>>>(entries, boff, off, epair, N);

  gemm_mfma_kernel<2><<<(N + 31) / 32, 256, 0, stream>>>(
      x, (const uint4*)wp1, as1, ad1, (void*)h1b, als, ald, N);
  agg1_kernel<<<(N + 3) / 4, 256, 0, stream>>>(h1b, als, ald, epair, off, b1, h1a, N);

  gemm_mfma_kernel<1><<<(N + 63) / 64, 256, 0, stream>>>(
      h1a, (const uint4*)wp2, as2, ad2, (void*)h2b, al2, nullptr, N);
  agg2_kernel<<<(N + 3) / 4, 256, 0, stream>>>(h2b, al2, epair, off, b2, lw, lb, out, N);
}

// Round 9
// 159.286 us; speedup vs baseline: 1.5549x; 1.1578x over previous
//
#include <hip/hip_runtime.h>
#include <hip/hip_fp16.h>

// GAT regression: 2-layer GAT + linear head.
// R16: layer-2 aggregation collapsed algebraically:
//   out[i] = sum_e alpha_e * s[src_e] + (b2.lin_w + lin_b),  s[j] = h2[j].lin_w
//   -> s computed in gemm2's epilogue (same shfl-reduce as logits); h2b never
//   stored; agg2 gathers ONE float2 (logit_src, s) per edge from a 400KB
//   L2-resident table instead of a 128B row (211MB -> 13MB of requests).
// Also: h1a stored f16 via cvt_pkrtz in agg1 (bit-identical to the pkrtz
// gemm2 applied anyway; halves agg1 O-write + gemm2 A-read).
// R15 retained: MFMA gemms (16x16x32 f16), fp8 e4m3 H1 rows, in-agg weights.
// Requires N < 65536 (16-bit packing). N = 50000.

#define LEAKY(x) ((x) > 0.f ? (x) : 0.2f * (x))

typedef float v2f __attribute__((ext_vector_type(2)));
typedef _Float16 f16x8 __attribute__((ext_vector_type(8)));
typedef __fp16 h16x2 __attribute__((ext_vector_type(2)));
typedef float f32x4 __attribute__((ext_vector_type(4)));

// ---------------- bucketed CSR build ----------------

template <int VPT>
__global__ __launch_bounds__(256) void bucket_cnt_kernel(const int* __restrict__ ei, int E, int n,
                                                         int* __restrict__ bc) {
  __shared__ int lc[256];
  int t = threadIdx.x;
  lc[t] = 0;
  __syncthreads();
  int base = blockIdx.x * (256 * VPT) + t;
  int tot = E + n;
#pragma unroll
  for (int u = 0; u < VPT; ++u) {
    int i = base + u * 256;
    if (i < tot) {
      int d = (i < E) ? ei[E + i] : (i - E);
      atomicAdd(&lc[d >> 8], 1);
    }
  }
  __syncthreads();
  if (lc[t]) atomicAdd(&bc[t], lc[t]);
}

__global__ __launch_bounds__(256) void bucket_scan_kernel(const int* __restrict__ bc,
                                                          int* __restrict__ boff,
                                                          int* __restrict__ bcur, int B,
                                                          int* __restrict__ off, int n, int Etot) {
  __shared__ int sm[256];
  int t = threadIdx.x;
  int v = (t < B) ? bc[t] : 0;
  sm[t] = v;
  __syncthreads();
  for (int s = 1; s < 256; s <<= 1) {
    int a = (t >= s) ? sm[t - s] : 0;
    __syncthreads();
    sm[t] += a;
    __syncthreads();
  }
  int excl = sm[t] - v;
  if (t < B) { boff[t] = excl; bcur[t] = excl; }
  if (t == 0) { boff[B] = Etot; off[n] = Etot; }
}

template <int VPT>
__global__ __launch_bounds__(256) void bucket_scatter_kernel(const int* __restrict__ ei, int E,
                                                             int n, int* __restrict__ bcur,
                                                             unsigned* __restrict__ entries) {
  __shared__ int lc[256];
  __shared__ int lbase[256];
  int t = threadIdx.x;
  lc[t] = 0;
  __syncthreads();
  int base = blockIdx.x * (256 * VPT) + t;
  int tot = E + n;
  int bb[VPT], ll[VPT];
  unsigned pk[VPT];
#pragma unroll
  for (int u = 0; u < VPT; ++u) {
    int i = base + u * 256;
    bb[u] = -1;
    if (i < tot) {
      int s, d;
      if (i < E) { s = ei[i]; d = ei[E + i]; }
      else       { s = d = i - E; }
      int b = d >> 8;
      bb[u] = b;
      ll[u] = atomicAdd(&lc[b], 1);
      pk[u] = (unsigned)s | ((unsigned)(d & 255) << 16);
    }
  }
  __syncthreads();
  if (lc[t]) lbase[t] = atomicAdd(&bcur[t], lc[t]);
  __syncthreads();
#pragma unroll
  for (int u = 0; u < VPT; ++u)
    if (bb[u] >= 0) entries[lbase[bb[u]] + ll[u]] = pk[u];
}

__global__ __launch_bounds__(256) void csr_build_kernel(const unsigned* __restrict__ entries,
                                                        const int* __restrict__ boff,
                                                        int* __restrict__ off,
                                                        unsigned* __restrict__ epair, int n) {
  __shared__ int hist[256];
  __shared__ int scn[256];
  __shared__ int cur[256];
  int b = blockIdx.x, t = threadIdx.x;
  int k0 = boff[b], k1 = boff[b + 1];
  hist[t] = 0;
  __syncthreads();
  for (int k = k0 + t; k < k1; k += 256) atomicAdd(&hist[(entries[k] >> 16) & 255], 1);
  __syncthreads();
  int v = hist[t];
  scn[t] = v;
  __syncthreads();
  for (int s = 1; s < 256; s <<= 1) {
    int a = (t >= s) ? scn[t - s] : 0;
    __syncthreads();
    scn[t] += a;
    __syncthreads();
  }
  int excl = scn[t] - v;
  int d = (b << 8) + t;
  if (d < n) off[d] = k0 + excl;
  cur[t] = k0 + excl;
  __syncthreads();
  unsigned dbase = (unsigned)(b << 8) << 16;
  for (int k = k0 + t; k < k1; k += 256) {
    unsigned e = entries[k];
    unsigned dl = (e >> 16) & 255;
    int p = atomicAdd(&cur[dl], 1);
    epair[p] = (e & 0xffffu) | (dbase + (dl << 16));
  }
}

// ---------------- W fragment pre-pack (f32 -> f16, fragment order) ----------

// element e = (((cn*4+kk)*4+g)*16+c)*8+i  stores  W[kk*32+g*8+i][cn*16+c]
__global__ __launch_bounds__(256) void wprep_kernel(const float* __restrict__ W1,
                                                    const float* __restrict__ W2,
                                                    unsigned short* __restrict__ Wp1,
                                                    unsigned short* __restrict__ Wp2) {
  int t = blockIdx.x * 256 + threadIdx.x;
  bool second = t >= 16384;
  int e = second ? t - 16384 : t;
  if (second && e >= 8192) return;
  const float* W = second ? W2 : W1;
  unsigned short* Wp = second ? Wp2 : Wp1;
  int M = second ? 64 : 128;
  int i = e & 7;
  int c = (e >> 3) & 15;
  int g = (e >> 7) & 3;
  int kk = (e >> 9) & 3;
  int cn = e >> 11;
  int k = kk * 32 + g * 8 + i;
  int col = cn * 16 + c;
  __half h = __float2half(W[k * M + col]);
  Wp[e] = *(unsigned short*)&h;
}

// ---------------- MFMA GEMM + logits ----------------

// HEADS==2: block = 4 waves = 2M x 2N(head); 32 rows, N=128, H out fp8; A=f32.
// HEADS==1: block = 4 waves = 4M; 64 rows, N=64; A=f16 (h1a); no H store;
//           epilogue emits gsrc[node]=(src_logit, s=h2.lin_w), adst2[node].
template <int HEADS, int AF16>
__global__ __launch_bounds__(256) void gemm_mfma_kernel(const void* __restrict__ X,
                                                        const uint4* __restrict__ Wp,
                                                        const float* __restrict__ a_src,
                                                        const float* __restrict__ a_dst,
                                                        const float* __restrict__ lin_w,
                                                        void* __restrict__ Hout,
                                                        float2* __restrict__ als,
                                                        float2* __restrict__ ald,
                                                        float* __restrict__ adst2, int n) {
  constexpr int WM = (HEADS == 2) ? 2 : 4;
  constexpr int ROWS = WM * 16;
  __shared__ float lgt[2][2][2][16];  // [wm][head][src/dst][row] (HEADS==2 only)
  int t = threadIdx.x;
  int wave = t >> 6, lane = t & 63;
  int wm, wn;
  if (HEADS == 2) { wm = wave >> 1; wn = wave & 1; } else { wm = wave; wn = 0; }
  int g = lane >> 4, c = lane & 15;
  int nb0 = blockIdx.x * ROWS;

  // ---- A fragments: row = lane&15, k = (lane>>4)*8 + i (+32*kk) ----
  int arow = nb0 + wm * 16 + c;
  int arc = arow < n ? arow : (n - 1);
  f16x8 af[4];
  if constexpr (AF16) {
    const unsigned short* xr = (const unsigned short*)X + (size_t)arc * 128 + g * 8;
#pragma unroll
    for (int kk = 0; kk < 4; ++kk) {
      union { uint4 u; f16x8 v; } A;
      A.u = *(const uint4*)(xr + kk * 32);
      af[kk] = A.v;
    }
  } else {
    const float* xr = (const float*)X + (size_t)arc * 128 + g * 8;
#pragma unroll
    for (int kk = 0; kk < 4; ++kk) {
      float4 x0 = *(const float4*)(xr + kk * 32);
      float4 x1 = *(const float4*)(xr + kk * 32 + 4);
      union { f16x8 v; h16x2 p[4]; } A;
      A.p[0] = __builtin_amdgcn_cvt_pkrtz(x0.x, x0.y);
      A.p[1] = __builtin_amdgcn_cvt_pkrtz(x0.z, x0.w);
      A.p[2] = __builtin_amdgcn_cvt_pkrtz(x1.x, x1.y);
      A.p[3] = __builtin_amdgcn_cvt_pkrtz(x1.z, x1.w);
      af[kk] = A.v;
    }
  }

  // ---- MFMA: 4 col-tiles x 4 k-steps ----
  f32x4 acc[4];
  f32x4 z = {0.f, 0.f, 0.f, 0.f};
#pragma unroll
  for (int cn = 0; cn < 4; ++cn) acc[cn] = z;
#pragma unroll
  for (int cn = 0; cn < 4; ++cn) {
    int cng = wn * 4 + cn;
#pragma unroll
    for (int kk = 0; kk < 4; ++kk) {
      union { uint4 u; f16x8 v; } B;
      B.u = Wp[(cng * 4 + kk) * 64 + lane];
      acc[cn] = __builtin_amdgcn_mfma_f32_16x16x32_f16(af[kk], B.v, acc[cn], 0, 0, 0);
    }
  }

  // ---- epilogue: H store + logit/s dots ----
  float asv[4], adv[4], lv[4];
#pragma unroll
  for (int cn = 0; cn < 4; ++cn) {
    int col_l = wn * 64 + cn * 16 + c;
    asv[cn] = a_src[col_l];
    adv[cn] = a_dst[col_l];
    if constexpr (HEADS == 1) lv[cn] = lin_w[col_l];
  }
  float ps[4] = {0.f, 0.f, 0.f, 0.f};
  float pd[4] = {0.f, 0.f, 0.f, 0.f};
  float ss[4] = {0.f, 0.f, 0.f, 0.f};
#pragma unroll
  for (int cn = 0; cn < 4; ++cn) {
#pragma unroll
    for (int r = 0; r < 4; ++r) {
      float v = acc[cn][r];
      ps[r] = fmaf(v, asv[cn], ps[r]);
      pd[r] = fmaf(v, adv[cn], pd[r]);
      if constexpr (HEADS == 1) ss[r] = fmaf(v, lv[cn], ss[r]);
      if constexpr (HEADS == 2) {
        int noder = nb0 + wm * 16 + g * 4 + r;
        int colg = wn * 64 + cn * 16 + c;
        if (noder < n) {
          int b8 = __builtin_amdgcn_cvt_pk_fp8_f32(v, v, 0, false);
          ((unsigned char*)Hout)[(size_t)noder * 128 + colg] = (unsigned char)(b8 & 0xff);
        }
      }
    }
  }
#pragma unroll
  for (int r = 0; r < 4; ++r) {
#pragma unroll
    for (int m = 1; m <= 8; m <<= 1) {
      ps[r] += __shfl_xor(ps[r], m, 64);
      pd[r] += __shfl_xor(pd[r], m, 64);
      if constexpr (HEADS == 1) ss[r] += __shfl_xor(ss[r], m, 64);
    }
  }
  if constexpr (HEADS == 2) {
    if (c == 0) {
#pragma unroll
      for (int r = 0; r < 4; ++r) {
        lgt[wm][wn][0][g * 4 + r] = ps[r];
        lgt[wm][wn][1][g * 4 + r] = pd[r];
      }
    }
    __syncthreads();
    if (t < 32) {
      int wmm = t >> 4, row = t & 15;
      int node = nb0 + wmm * 16 + row;
      if (node < n) {
        als[node] = make_float2(lgt[wmm][0][0][row], lgt[wmm][1][0][row]);
        ald[node] = make_float2(lgt[wmm][0][1][row], lgt[wmm][1][1][row]);
      }
    }
  } else {
    if (c == 0) {
#pragma unroll
      for (int r = 0; r < 4; ++r) {
        int node = nb0 + wm * 16 + g * 4 + r;
        if (node < n) {
          als[node] = make_float2(ps[r], ss[r]);  // (src logit, s = h2.lin_w)
          adst2[node] = pd[r];
        }
      }
    }
  }
}

// ---------------- aggregation ----------------

// layer 1 (fp8 rows, 128B): R13 structure; O written as f16 (pkrtz).
__global__ __launch_bounds__(256) void agg1_kernel(const unsigned char* __restrict__ Hb8,
                                                   const float2* __restrict__ als,
                                                   const float2* __restrict__ ald,
                                                   const unsigned* __restrict__ epair,
                                                   const int* __restrict__ off,
                                                   const float* __restrict__ b1,
                                                   unsigned* __restrict__ O16, int n) {
  __shared__ float wlds[4][128];
  int wid = (blockIdx.x * 256 + threadIdx.x) >> 6;
  int lane = threadIdx.x & 63;
  if (wid >= n) return;
  wid = __builtin_amdgcn_readfirstlane(wid);
  int wslot = (threadIdx.x >> 6) & 3;
  int half = lane >> 5;
  int k0 = off[wid], k1 = off[wid + 1];
  const unsigned short* Hu = (const unsigned short*)Hb8;
  float2 advv = ald[wid];
  float* wrow = &wlds[wslot][half << 6];

  float ax = 0.f, ay = 0.f, den = 0.f;

  for (int kb = k0; kb < k1; kb += 64) {
    int rem = min(k1 - kb, 64);
    int e = kb + (lane < rem ? lane : rem - 1);
    unsigned pp = epair[e];
    float2 l = als[pp & 0xffffu];
    float g0 = __expf(LEAKY(l.x + advv.x));
    float g1 = __expf(LEAKY(l.y + advv.y));
    wlds[wslot][lane] = g0;
    wlds[wslot][64 + lane] = g1;

#define EDGE1(jj)                                                                   \
  {                                                                                 \
    unsigned p = ((unsigned)__builtin_amdgcn_readlane((int)pp, (jj))) & 0xffffu;    \
    float w = wrow[(jj)];                                                           \
    unsigned short hv = Hu[(p << 6) | (unsigned)lane];                              \
    v2f hf = __builtin_amdgcn_cvt_pk_f32_fp8((int)hv, false);                       \
    den += w;                                                                       \
    ax = fmaf(hf.x, w, ax);                                                         \
    ay = fmaf(hf.y, w, ay);                                                         \
  }

    int nb = rem >> 3;
    for (int b = 0; b < nb; ++b) {
      int jb = b << 3;
#pragma unroll
      for (int j = 0; j < 8; ++j) EDGE1(jb + j);
    }
    for (int jj = nb << 3; jj < rem; ++jj) EDGE1(jj);
#undef EDGE1
  }

  float inv = 1.f / (den + 1e-16f);
  float2 bv = ((const float2*)b1)[lane];
  float r0 = ax * inv + bv.x;
  float r1 = ay * inv + bv.y;
  r0 = r0 > 0.f ? r0 : (__expf(r0) - 1.f);
  r1 = r1 > 0.f ? r1 : (__expf(r1) - 1.f);
  union { h16x2 h; unsigned u; } cv;
  cv.h = __builtin_amdgcn_cvt_pkrtz(r0, r1);
  O16[((size_t)wid << 6) + (unsigned)lane] = cv.u;
}

// layer 2 + head, collapsed: per edge gather (logit_src, s) float2; scalar agg.
__global__ __launch_bounds__(256) void agg2_kernel(const float2* __restrict__ gsrc,
                                                   const float* __restrict__ adst2,
                                                   const unsigned* __restrict__ epair,
                                                   const int* __restrict__ off,
                                                   const float* __restrict__ b2,
                                                   const float* __restrict__ lin_w,
                                                   const float* __restrict__ lin_b,
                                                   float* __restrict__ out, int n) {
  int wid = (blockIdx.x * 256 + threadIdx.x) >> 6;
  int lane = threadIdx.x & 63;
  if (wid >= n) return;
  wid = __builtin_amdgcn_readfirstlane(wid);
  int k0 = off[wid], k1 = off[wid + 1];
  float adv = adst2[wid];

  float num = 0.f, den = 0.f;
  for (int kb = k0; kb < k1; kb += 64) {
    int e = kb + lane;
    bool ok = e < k1;
    unsigned pp = epair[ok ? e : k0];
    float2 g = gsrc[pp & 0xffffu];
    float w = ok ? __expf(LEAKY(g.x + adv)) : 0.f;
    num = fmaf(w, g.y, num);
    den += w;
  }
  float bt = b2[lane] * lin_w[lane];  // lanes cover all 64 ch -> b2.lin_w
#pragma unroll
  for (int m = 1; m <= 32; m <<= 1) {
    num += __shfl_xor(num, m, 64);
    den += __shfl_xor(den, m, 64);
    bt  += __shfl_xor(bt, m, 64);
  }
  if (lane == 0) out[wid] = num / (den + 1e-16f) + bt + lin_b[0];
}

// ---------------- launcher ----------------

static inline size_t alignup(size_t v) { return (v + 255) & ~(size_t)255; }

extern "C" void kernel_launch(void* const* d_in, const int* in_sizes, int n_in,
                              void* d_out, int out_size, void* d_ws, size_t ws_size,
                              hipStream_t stream) {
  const float* x   = (const float*)d_in[0];
  const int*   ei  = (const int*)d_in[1];
  const float* W1  = (const float*)d_in[2];
  const float* as1 = (const float*)d_in[3];
  const float* ad1 = (const float*)d_in[4];
  const float* b1  = (const float*)d_in[5];
  const float* W2  = (const float*)d_in[6];
  const float* as2 = (const float*)d_in[7];
  const float* ad2 = (const float*)d_in[8];
  const float* b2  = (const float*)d_in[9];
  const float* lw  = (const float*)d_in[10];
  const float* lb  = (const float*)d_in[11];
  float* out = (float*)d_out;

  const int N = out_size;          // 50000
  const int E = in_sizes[1] / 2;   // 1600000
  const int Etot = E + N;
  const int B = (N + 255) >> 8;    // 196 buckets

  char* p = (char*)d_ws;
  int* bcnt = (int*)p;  p += alignup((size_t)(B + 1) * 4);
  int* boff = (int*)p;  p += alignup((size_t)(B + 1) * 4);
  int* bcur = (int*)p;  p += alignup((size_t)B * 4);
  unsigned* entries = (unsigned*)p; p += alignup((size_t)Etot * 4);
  int* off  = (int*)p;  p += alignup((size_t)(N + 1) * 4);
  unsigned* epair = (unsigned*)p; p += alignup((size_t)Etot * 4);
  float2* als = (float2*)p; p += alignup((size_t)N * 8);
  float2* ald = (float2*)p; p += alignup((size_t)N * 8);
  float2* gsrc = (float2*)p; p += alignup((size_t)N * 8);
  float* adst2 = (float*)p; p += alignup((size_t)N * 4);
  unsigned* h1a = (unsigned*)p; p += alignup((size_t)N * 128 * 2);   // f16 rows
  unsigned char* h1b = (unsigned char*)p; p += alignup((size_t)N * 128);
  unsigned short* wp1 = (unsigned short*)p; p += alignup((size_t)16384 * 2);
  unsigned short* wp2 = (unsigned short*)p; p += alignup((size_t)8192 * 2);

  hipMemsetAsync(bcnt, 0, (size_t)(B + 1) * sizeof(int), stream);

  constexpr int VPT = 8;
  int egrid = (Etot + 256 * VPT - 1) / (256 * VPT);

  wprep_kernel<<<96, 256, 0, stream>>>(W1, W2, wp1, wp2);
  bucket_cnt_kernel<VPT><<<egrid, 256, 0, stream>>>(ei, E, N, bcnt);
  bucket_scan_kernel<<<1, 256, 0, stream>>>(bcnt, boff, bcur, B, off, N, Etot);
  bucket_scatter_kernel<VPT><<<egrid, 256, 0, stream>>>(ei, E, N, bcur, entries);
  csr_build_kernel<<<B, 256, 0, stream>>>(entries, boff, off, epair, N);

  gemm_mfma_kernel<2, 0><<<(N + 31) / 32, 256, 0, stream>>>(
      (const void*)x, (const uint4*)wp1, as1, ad1, nullptr, (void*)h1b, als, ald, nullptr, N);
  agg1_kernel<<<(N + 3) / 4, 256, 0, stream>>>(h1b, als, ald, epair, off, b1, h1a, N);

  gemm_mfma_kernel<1, 1><<<(N + 63) / 64, 256, 0, stream>>>(
      (const void*)h1a, (const uint4*)wp2, as2, ad2, lw, nullptr, gsrc, nullptr, adst2, N);
  agg2_kernel<<<(N + 3) / 4, 256, 0, stream>>>(gsrc, adst2, epair, off, b2, lw, lb, out, N);
}

// Round 10
// 152.653 us; speedup vs baseline: 1.6224x; 1.0435x over previous
//
#include <hip/hip_runtime.h>
#include <hip/hip_fp16.h>

// GAT regression: 2-layer GAT + linear head.
// R17: (1) gemm2 DELETED — h2 only feeds 3 dot products, so wprep precomputes
//      v_src2=W2·a_src2, v_dst2=W2·a_dst2, v_lin=W2·lin_w (3x128 f32) and
//      agg1's epilogue dots its elu output with them (6 fma + 3 butterflies),
//      writing gsrc=(logit_src2, s) + adst2 per node. h1a never materialized.
//      (2) gemm1 A-fragments via LDS staging: coalesced float4 stage into a
//      +4-float padded tile (2-way bank alias = free), ds_read_b128 frags.
// R16 retained: scalar agg2 on the (logit,s) table; fp8 e4m3 H1 rows; in-agg
// softmax weights; MFMA 16x16x32 f16 with fragment-packed W1.
// Requires N < 65536 (16-bit packing). N = 50000.

#define LEAKY(x) ((x) > 0.f ? (x) : 0.2f * (x))

typedef float v2f __attribute__((ext_vector_type(2)));
typedef _Float16 f16x8 __attribute__((ext_vector_type(8)));
typedef __fp16 h16x2 __attribute__((ext_vector_type(2)));
typedef float f32x4 __attribute__((ext_vector_type(4)));

// ---------------- bucketed CSR build ----------------

template <int VPT>
__global__ __launch_bounds__(256) void bucket_cnt_kernel(const int* __restrict__ ei, int E, int n,
                                                         int* __restrict__ bc) {
  __shared__ int lc[256];
  int t = threadIdx.x;
  lc[t] = 0;
  __syncthreads();
  int base = blockIdx.x * (256 * VPT) + t;
  int tot = E + n;
#pragma unroll
  for (int u = 0; u < VPT; ++u) {
    int i = base + u * 256;
    if (i < tot) {
      int d = (i < E) ? ei[E + i] : (i - E);
      atomicAdd(&lc[d >> 8], 1);
    }
  }
  __syncthreads();
  if (lc[t]) atomicAdd(&bc[t], lc[t]);
}

__global__ __launch_bounds__(256) void bucket_scan_kernel(const int* __restrict__ bc,
                                                          int* __restrict__ boff,
                                                          int* __restrict__ bcur, int B,
                                                          int* __restrict__ off, int n, int Etot) {
  __shared__ int sm[256];
  int t = threadIdx.x;
  int v = (t < B) ? bc[t] : 0;
  sm[t] = v;
  __syncthreads();
  for (int s = 1; s < 256; s <<= 1) {
    int a = (t >= s) ? sm[t - s] : 0;
    __syncthreads();
    sm[t] += a;
    __syncthreads();
  }
  int excl = sm[t] - v;
  if (t < B) { boff[t] = excl; bcur[t] = excl; }
  if (t == 0) { boff[B] = Etot; off[n] = Etot; }
}

template <int VPT>
__global__ __launch_bounds__(256) void bucket_scatter_kernel(const int* __restrict__ ei, int E,
                                                             int n, int* __restrict__ bcur,
                                                             unsigned* __restrict__ entries) {
  __shared__ int lc[256];
  __shared__ int lbase[256];
  int t = threadIdx.x;
  lc[t] = 0;
  __syncthreads();
  int base = blockIdx.x * (256 * VPT) + t;
  int tot = E + n;
  int bb[VPT], ll[VPT];
  unsigned pk[VPT];
#pragma unroll
  for (int u = 0; u < VPT; ++u) {
    int i = base + u * 256;
    bb[u] = -1;
    if (i < tot) {
      int s, d;
      if (i < E) { s = ei[i]; d = ei[E + i]; }
      else       { s = d = i - E; }
      int b = d >> 8;
      bb[u] = b;
      ll[u] = atomicAdd(&lc[b], 1);
      pk[u] = (unsigned)s | ((unsigned)(d & 255) << 16);
    }
  }
  __syncthreads();
  if (lc[t]) lbase[t] = atomicAdd(&bcur[t], lc[t]);
  __syncthreads();
#pragma unroll
  for (int u = 0; u < VPT; ++u)
    if (bb[u] >= 0) entries[lbase[bb[u]] + ll[u]] = pk[u];
}

__global__ __launch_bounds__(256) void csr_build_kernel(const unsigned* __restrict__ entries,
                                                        const int* __restrict__ boff,
                                                        int* __restrict__ off,
                                                        unsigned* __restrict__ epair, int n) {
  __shared__ int hist[256];
  __shared__ int scn[256];
  __shared__ int cur[256];
  int b = blockIdx.x, t = threadIdx.x;
  int k0 = boff[b], k1 = boff[b + 1];
  hist[t] = 0;
  __syncthreads();
  for (int k = k0 + t; k < k1; k += 256) atomicAdd(&hist[(entries[k] >> 16) & 255], 1);
  __syncthreads();
  int v = hist[t];
  scn[t] = v;
  __syncthreads();
  for (int s = 1; s < 256; s <<= 1) {
    int a = (t >= s) ? scn[t - s] : 0;
    __syncthreads();
    scn[t] += a;
    __syncthreads();
  }
  int excl = scn[t] - v;
  int d = (b << 8) + t;
  if (d < n) off[d] = k0 + excl;
  cur[t] = k0 + excl;
  __syncthreads();
  unsigned dbase = (unsigned)(b << 8) << 16;
  for (int k = k0 + t; k < k1; k += 256) {
    unsigned e = entries[k];
    unsigned dl = (e >> 16) & 255;
    int p = atomicAdd(&cur[dl], 1);
    epair[p] = (e & 0xffffu) | (dbase + (dl << 16));
  }
}

// ---------------- W prep: W1 fragment pack + layer-2 projection vectors -----

// W1 pack: element e = (((cn*4+kk)*4+g)*16+c)*8+i  stores W1[kk*32+g*8+i][cn*16+c]
// v-vectors: v_src2[k]=W2[k,:]·a_src2, v_dst2[k]=W2[k,:]·a_dst2, v_lin[k]=W2[k,:]·lin_w
__global__ __launch_bounds__(256) void wprep_kernel(const float* __restrict__ W1,
                                                    const float* __restrict__ W2,
                                                    const float* __restrict__ as2,
                                                    const float* __restrict__ ad2,
                                                    const float* __restrict__ lw,
                                                    unsigned short* __restrict__ Wp1,
                                                    float* __restrict__ vsrc2,
                                                    float* __restrict__ vdst2,
                                                    float* __restrict__ vlin) {
  int t = blockIdx.x * 256 + threadIdx.x;
  if (t < 16384) {
    int e = t;
    int i = e & 7;
    int c = (e >> 3) & 15;
    int g = (e >> 7) & 3;
    int kk = (e >> 9) & 3;
    int cn = e >> 11;
    int k = kk * 32 + g * 8 + i;
    int col = cn * 16 + c;
    __half h = __float2half(W1[k * 128 + col]);
    Wp1[e] = *(unsigned short*)&h;
  } else if (t < 16384 + 128) {
    int k = t - 16384;
    float a = 0.f, b = 0.f, s = 0.f;
    for (int cc = 0; cc < 64; ++cc) {
      float w = W2[k * 64 + cc];
      a = fmaf(w, as2[cc], a);
      b = fmaf(w, ad2[cc], b);
      s = fmaf(w, lw[cc], s);
    }
    vsrc2[k] = a;
    vdst2[k] = b;
    vlin[k] = s;
  }
}

// ---------------- MFMA GEMM1 + logits (LDS-staged A) ----------------

// block = 4 waves = 2M x 2N(head); 32 rows, N=128, H out fp8 e4m3.
__global__ __launch_bounds__(256) void gemm1_kernel(const float* __restrict__ X,
                                                    const uint4* __restrict__ Wp,
                                                    const float* __restrict__ a_src,
                                                    const float* __restrict__ a_dst,
                                                    unsigned char* __restrict__ Hout,
                                                    float2* __restrict__ als,
                                                    float2* __restrict__ ald, int n) {
  __shared__ float Xl[32 * 132];      // 32 rows x 128 f32, +4 pad (bank-friendly)
  __shared__ float lgt[2][2][2][16];  // [wm][head][src/dst][row]
  int t = threadIdx.x;
  int wave = t >> 6, lane = t & 63;
  int wm = wave >> 1, wn = wave & 1;
  int g = lane >> 4, c = lane & 15;
  int nb0 = blockIdx.x * 32;

  // ---- stage 32 rows coalesced (float4), padded rows of 132 floats ----
  {
    const float4* Xg = (const float4*)X;
    float4* Xs = (float4*)Xl;
#pragma unroll
    for (int u = 0; u < 4; ++u) {
      int idx = u * 256 + t;          // 0..1023 float4 slots
      int r = idx >> 5, c4 = idx & 31;
      int row = nb0 + r;
      int rc = row < n ? row : (n - 1);
      Xs[r * 33 + c4] = Xg[(size_t)rc * 32 + c4];
    }
  }
  __syncthreads();

  // ---- A fragments from LDS: row = wm*16+c, k = g*8 + i (+32*kk) ----
  f16x8 af[4];
  const float* xr = Xl + (wm * 16 + c) * 132 + g * 8;
#pragma unroll
  for (int kk = 0; kk < 4; ++kk) {
    float4 x0 = *(const float4*)(xr + kk * 32);
    float4 x1 = *(const float4*)(xr + kk * 32 + 4);
    union { f16x8 v; h16x2 p[4]; } A;
    A.p[0] = __builtin_amdgcn_cvt_pkrtz(x0.x, x0.y);
    A.p[1] = __builtin_amdgcn_cvt_pkrtz(x0.z, x0.w);
    A.p[2] = __builtin_amdgcn_cvt_pkrtz(x1.x, x1.y);
    A.p[3] = __builtin_amdgcn_cvt_pkrtz(x1.z, x1.w);
    af[kk] = A.v;
  }

  // ---- MFMA: 4 col-tiles x 4 k-steps ----
  f32x4 acc[4];
  f32x4 z = {0.f, 0.f, 0.f, 0.f};
#pragma unroll
  for (int cn = 0; cn < 4; ++cn) acc[cn] = z;
#pragma unroll
  for (int cn = 0; cn < 4; ++cn) {
    int cng = wn * 4 + cn;
#pragma unroll
    for (int kk = 0; kk < 4; ++kk) {
      union { uint4 u; f16x8 v; } B;
      B.u = Wp[(cng * 4 + kk) * 64 + lane];
      acc[cn] = __builtin_amdgcn_mfma_f32_16x16x32_f16(af[kk], B.v, acc[cn], 0, 0, 0);
    }
  }

  // ---- epilogue: fp8 H store + logit dots ----
  float asv[4], adv[4];
#pragma unroll
  for (int cn = 0; cn < 4; ++cn) {
    int col_l = wn * 64 + cn * 16 + c;
    asv[cn] = a_src[col_l];
    adv[cn] = a_dst[col_l];
  }
  float ps[4] = {0.f, 0.f, 0.f, 0.f};
  float pd[4] = {0.f, 0.f, 0.f, 0.f};
#pragma unroll
  for (int cn = 0; cn < 4; ++cn) {
#pragma unroll
    for (int r = 0; r < 4; ++r) {
      float v = acc[cn][r];
      ps[r] = fmaf(v, asv[cn], ps[r]);
      pd[r] = fmaf(v, adv[cn], pd[r]);
      int noder = nb0 + wm * 16 + g * 4 + r;
      int colg = wn * 64 + cn * 16 + c;
      if (noder < n) {
        int b8 = __builtin_amdgcn_cvt_pk_fp8_f32(v, v, 0, false);
        Hout[(size_t)noder * 128 + colg] = (unsigned char)(b8 & 0xff);
      }
    }
  }
#pragma unroll
  for (int r = 0; r < 4; ++r) {
#pragma unroll
    for (int m = 1; m <= 8; m <<= 1) {
      ps[r] += __shfl_xor(ps[r], m, 64);
      pd[r] += __shfl_xor(pd[r], m, 64);
    }
  }
  if (c == 0) {
#pragma unroll
    for (int r = 0; r < 4; ++r) {
      lgt[wm][wn][0][g * 4 + r] = ps[r];
      lgt[wm][wn][1][g * 4 + r] = pd[r];
    }
  }
  __syncthreads();
  if (t < 32) {
    int wmm = t >> 4, row = t & 15;
    int node = nb0 + wmm * 16 + row;
    if (node < n) {
      als[node] = make_float2(lgt[wmm][0][0][row], lgt[wmm][1][0][row]);
      ald[node] = make_float2(lgt[wmm][0][1][row], lgt[wmm][1][1][row]);
    }
  }
}

// ---------------- aggregation ----------------

// layer 1 (fp8 rows, 128B) + fused layer-2 projection epilogue.
__global__ __launch_bounds__(256) void agg1_kernel(const unsigned char* __restrict__ Hb8,
                                                   const float2* __restrict__ als,
                                                   const float2* __restrict__ ald,
                                                   const unsigned* __restrict__ epair,
                                                   const int* __restrict__ off,
                                                   const float* __restrict__ b1,
                                                   const float* __restrict__ vsrc2,
                                                   const float* __restrict__ vdst2,
                                                   const float* __restrict__ vlin,
                                                   float2* __restrict__ gsrc,
                                                   float* __restrict__ adst2, int n) {
  __shared__ float wlds[4][128];
  int wid = (blockIdx.x * 256 + threadIdx.x) >> 6;
  int lane = threadIdx.x & 63;
  if (wid >= n) return;
  wid = __builtin_amdgcn_readfirstlane(wid);
  int wslot = (threadIdx.x >> 6) & 3;
  int half = lane >> 5;
  int k0 = off[wid], k1 = off[wid + 1];
  const unsigned short* Hu = (const unsigned short*)Hb8;
  float2 advv = ald[wid];
  float* wrow = &wlds[wslot][half << 6];

  float ax = 0.f, ay = 0.f, den = 0.f;

  for (int kb = k0; kb < k1; kb += 64) {
    int rem = min(k1 - kb, 64);
    int e = kb + (lane < rem ? lane : rem - 1);
    unsigned pp = epair[e];
    float2 l = als[pp & 0xffffu];
    float g0 = __expf(LEAKY(l.x + advv.x));
    float g1 = __expf(LEAKY(l.y + advv.y));
    wlds[wslot][lane] = g0;
    wlds[wslot][64 + lane] = g1;

#define EDGE1(jj)                                                                   \
  {                                                                                 \
    unsigned p = ((unsigned)__builtin_amdgcn_readlane((int)pp, (jj))) & 0xffffu;    \
    float w = wrow[(jj)];                                                           \
    unsigned short hv = Hu[(p << 6) | (unsigned)lane];                              \
    v2f hf = __builtin_amdgcn_cvt_pk_f32_fp8((int)hv, false);                       \
    den += w;                                                                       \
    ax = fmaf(hf.x, w, ax);                                                         \
    ay = fmaf(hf.y, w, ay);                                                         \
  }

    int nb = rem >> 3;
    for (int b = 0; b < nb; ++b) {
      int jb = b << 3;
#pragma unroll
      for (int j = 0; j < 8; ++j) EDGE1(jb + j);
    }
    for (int jj = nb << 3; jj < rem; ++jj) EDGE1(jj);
#undef EDGE1
  }

  // elu(out + b1), then project onto the three layer-2 vectors.
  float inv = 1.f / (den + 1e-16f);
  float2 bv = ((const float2*)b1)[lane];
  float r0 = ax * inv + bv.x;
  float r1 = ay * inv + bv.y;
  r0 = r0 > 0.f ? r0 : (__expf(r0) - 1.f);
  r1 = r1 > 0.f ? r1 : (__expf(r1) - 1.f);
  float2 vs = ((const float2*)vsrc2)[lane];
  float2 vd = ((const float2*)vdst2)[lane];
  float2 vl = ((const float2*)vlin)[lane];
  float ps = r0 * vs.x + r1 * vs.y;
  float pd = r0 * vd.x + r1 * vd.y;
  float sv = r0 * vl.x + r1 * vl.y;
#pragma unroll
  for (int m = 1; m <= 32; m <<= 1) {
    ps += __shfl_xor(ps, m, 64);
    pd += __shfl_xor(pd, m, 64);
    sv += __shfl_xor(sv, m, 64);
  }
  if (lane == 0) {
    gsrc[wid] = make_float2(ps, sv);
    adst2[wid] = pd;
  }
}

// layer 2 + head, collapsed: per edge gather (logit_src, s) float2; scalar agg.
__global__ __launch_bounds__(256) void agg2_kernel(const float2* __restrict__ gsrc,
                                                   const float* __restrict__ adst2,
                                                   const unsigned* __restrict__ epair,
                                                   const int* __restrict__ off,
                                                   const float* __restrict__ b2,
                                                   const float* __restrict__ lin_w,
                                                   const float* __restrict__ lin_b,
                                                   float* __restrict__ out, int n) {
  int wid = (blockIdx.x * 256 + threadIdx.x) >> 6;
  int lane = threadIdx.x & 63;
  if (wid >= n) return;
  wid = __builtin_amdgcn_readfirstlane(wid);
  int k0 = off[wid], k1 = off[wid + 1];
  float adv = adst2[wid];

  float num = 0.f, den = 0.f;
  for (int kb = k0; kb < k1; kb += 64) {
    int e = kb + lane;
    bool ok = e < k1;
    unsigned pp = epair[ok ? e : k0];
    float2 g = gsrc[pp & 0xffffu];
    float w = ok ? __expf(LEAKY(g.x + adv)) : 0.f;
    num = fmaf(w, g.y, num);
    den += w;
  }
  float bt = b2[lane] * lin_w[lane];  // lanes cover all 64 ch -> b2.lin_w
#pragma unroll
  for (int m = 1; m <= 32; m <<= 1) {
    num += __shfl_xor(num, m, 64);
    den += __shfl_xor(den, m, 64);
    bt  += __shfl_xor(bt, m, 64);
  }
  if (lane == 0) out[wid] = num / (den + 1e-16f) + bt + lin_b[0];
}

// ---------------- launcher ----------------

static inline size_t alignup(size_t v) { return (v + 255) & ~(size_t)255; }

extern "C" void kernel_launch(void* const* d_in, const int* in_sizes, int n_in,
                              void* d_out, int out_size, void* d_ws, size_t ws_size,
                              hipStream_t stream) {
  const float* x   = (const float*)d_in[0];
  const int*   ei  = (const int*)d_in[1];
  const float* W1  = (const float*)d_in[2];
  const float* as1 = (const float*)d_in[3];
  const float* ad1 = (const float*)d_in[4];
  const float* b1  = (const float*)d_in[5];
  const float* W2  = (const float*)d_in[6];
  const float* as2 = (const float*)d_in[7];
  const float* ad2 = (const float*)d_in[8];
  const float* b2  = (const float*)d_in[9];
  const float* lw  = (const float*)d_in[10];
  const float* lb  = (const float*)d_in[11];
  float* out = (float*)d_out;

  const int N = out_size;          // 50000
  const int E = in_sizes[1] / 2;   // 1600000
  const int Etot = E + N;
  const int B = (N + 255) >> 8;    // 196 buckets

  char* p = (char*)d_ws;
  int* bcnt = (int*)p;  p += alignup((size_t)(B + 1) * 4);
  int* boff = (int*)p;  p += alignup((size_t)(B + 1) * 4);
  int* bcur = (int*)p;  p += alignup((size_t)B * 4);
  unsigned* entries = (unsigned*)p; p += alignup((size_t)Etot * 4);
  int* off  = (int*)p;  p += alignup((size_t)(N + 1) * 4);
  unsigned* epair = (unsigned*)p; p += alignup((size_t)Etot * 4);
  float2* als = (float2*)p; p += alignup((size_t)N * 8);
  float2* ald = (float2*)p; p += alignup((size_t)N * 8);
  float2* gsrc = (float2*)p; p += alignup((size_t)N * 8);
  float* adst2 = (float*)p; p += alignup((size_t)N * 4);
  unsigned char* h1b = (unsigned char*)p; p += alignup((size_t)N * 128);
  unsigned short* wp1 = (unsigned short*)p; p += alignup((size_t)16384 * 2);
  float* vsrc2 = (float*)p; p += alignup((size_t)128 * 4);
  float* vdst2 = (float*)p; p += alignup((size_t)128 * 4);
  float* vlin  = (float*)p; p += alignup((size_t)128 * 4);

  hipMemsetAsync(bcnt, 0, (size_t)(B + 1) * sizeof(int), stream);

  constexpr int VPT = 8;
  int egrid = (Etot + 256 * VPT - 1) / (256 * VPT);

  wprep_kernel<<<65, 256, 0, stream>>>(W1, W2, as2, ad2, lw, wp1, vsrc2, vdst2, vlin);
  bucket_cnt_kernel<VPT><<<egrid, 256, 0, stream>>>(ei, E, N, bcnt);
  bucket_scan_kernel<<<1, 256, 0, stream>>>(bcnt, boff, bcur, B, off, N, Etot);
  bucket_scatter_kernel<VPT><<<egrid, 256, 0, stream>>>(ei, E, N, bcur, entries);
  csr_build_kernel<<<B, 256, 0, stream>>>(entries, boff, off, epair, N);

  gemm1_kernel<<<(N + 31) / 32, 256, 0, stream>>>(
      x, (const uint4*)wp1, as1, ad1, h1b, als, ald, N);
  agg1_kernel<<<(N + 3) / 4, 256, 0, stream>>>(h1b, als, ald, epair, off, b1,
                                               vsrc2, vdst2, vlin, gsrc, adst2, N);
  agg2_kernel<<<(N + 3) / 4, 256, 0, stream>>>(gsrc, adst2, epair, off, b2, lw, lb, out, N);
}